// Round 2
// baseline (29756.586 us; speedup 1.0000x reference)
//
#include <hip/hip_runtime.h>
#include <hip/hip_cooperative_groups.h>
#include <cstdint>

namespace cg = cooperative_groups;

#define HDIM   1536
#define DIN    256
#define NSTEP  1008     // (T-1)*B = 63*16
#define NWG    256
#define TPB    512
#define UPW    6        // hidden units per WG per layer (256*6 = 1536)

#define XN      256                 // x elements per step
#define SGH0    XN                  // stage offset of h0
#define SGH1    (XN + HDIM)         // stage offset of h1
#define STAGE_N (XN + 2*HDIM)       // 3328 floats

// ws layout (32-bit words):
//   [0    .. 3071]  h0 exchange, fp32, [2 parities][1536]
//   [3072 .. 6143]  h1 exchange, fp32, [2 parities][1536]
//   [6144]          dtype flag: 1 = fp32 inputs, 0 = bf16 inputs
#define WS_H0   0
#define WS_H1   3072
#define WS_FLAG 6144

__device__ __forceinline__ float bflo(uint32_t p){ union{uint32_t u; float f;} v; v.u = p << 16; return v.f; }
__device__ __forceinline__ float bfhi(uint32_t p){ union{uint32_t u; float f;} v; v.u = p & 0xffff0000u; return v.f; }
__device__ __forceinline__ float bf2f(uint16_t b){ union{uint32_t u; float f;} v; v.u = ((uint32_t)b) << 16; return v.f; }
__device__ __forceinline__ uint16_t f2bf(float f){
    union{float f; uint32_t u;} v; v.f = f;
    uint32_t r = v.u + 0x7fffu + ((v.u >> 16) & 1u);   // RNE
    return (uint16_t)(r >> 16);
}
__device__ __forceinline__ uint32_t packbf(float lo, float hi){
    return (uint32_t)f2bf(lo) | ((uint32_t)f2bf(hi) << 16);
}

// sum across all 64 lanes, result in every lane
__device__ __forceinline__ float wave_sum(float x){
    #pragma unroll
    for (int o = 1; o < 64; o <<= 1) x += __shfl_xor(x, o, 64);
    return x;
}

// ---------------------------------------------------------------------------
// dtype probe: inspect first 256 words of W_hh0. For bf16-packed data the low
// 16 bits of each word are a valid small-Gaussian bf16 (exp field in
// [0x70,0x7C] or 0). For fp32 data they are mantissa bits (uniform).
// ---------------------------------------------------------------------------
__global__ void dtype_probe(const uint32_t* __restrict__ w, uint32_t* __restrict__ ws){
    const int t = threadIdx.x;   // 64 threads
    int cnt = 0;
    #pragma unroll
    for (int j = 0; j < 4; ++j){
        const uint32_t v = w[t*4 + j];
        const uint32_t e = (v >> 7) & 0xFFu;
        if (e == 0u || (e >= 0x70u && e <= 0x7Cu)) cnt++;
    }
    #pragma unroll
    for (int o = 1; o < 64; o <<= 1) cnt += __shfl_xor(cnt, o, 64);
    if (t == 0)
        ws[WS_FLAG] = (cnt < 128) ? 1u : 0u;   // sparse in-window => fp32
}

__global__ __launch_bounds__(TPB, 2)
void lstm_seq_kernel(const void* __restrict__ batch_,
                     const void* __restrict__ Wih0_,
                     const void* __restrict__ Whh0_,
                     const void* __restrict__ bih0_,
                     const void* __restrict__ bhh0_,
                     const void* __restrict__ Wih1_,
                     const void* __restrict__ Whh1_,
                     const void* __restrict__ bih1_,
                     const void* __restrict__ bhh1_,
                     void* __restrict__ out_,
                     uint32_t* __restrict__ ws)
{
    __shared__ uint32_t lds_w[8*3*8*64];     // L1 rows, h0-chunks 0..7 (packed bf16)
    __shared__ float    lds_stage[STAGE_N];  // x ++ h0 ++ h1 (fp32)
    __shared__ float    lds_pre[48];         // 24 L0 + 24 L1 pre-activations
    __shared__ float    lds_b[48];           // fused biases
    __shared__ float    lds_c[12];           // c-state
    __shared__ float    lds_hout[12];        // h-state (fp32)

    const int g   = blockIdx.x;
    const int tid = threadIdx.x;
    const int w   = tid >> 6;
    const int l   = tid & 63;

    const uint32_t fp32in = __hip_atomic_load(&ws[WS_FLAG],
                             __ATOMIC_RELAXED, __HIP_MEMORY_SCOPE_AGENT);
    float* wsf = (float*)ws;

    // ---------------- init ----------------
    if (tid < 24){
        const int uu = tid >> 2, gate = tid & 3;
        const int grow = gate*HDIM + g*UPW + uu;
        if (fp32in){
            lds_b[tid]      = ((const float*)bih0_)[grow] + ((const float*)bhh0_)[grow];
            lds_b[24 + tid] = ((const float*)bih1_)[grow] + ((const float*)bhh1_)[grow];
        } else {
            lds_b[tid]      = bf2f(((const uint16_t*)bih0_)[grow]) + bf2f(((const uint16_t*)bhh0_)[grow]);
            lds_b[24 + tid] = bf2f(((const uint16_t*)bih1_)[grow]) + bf2f(((const uint16_t*)bhh1_)[grow]);
        }
        // zero own h-exchange slots in all 4 buffers (layer x parity)
        const int layer = tid / 12, rem = tid % 12;
        const int par = rem / 6, k = rem % 6;
        __hip_atomic_store(&wsf[(layer ? WS_H1 : WS_H0) + par*HDIM + g*UPW + k], 0.0f,
                           __ATOMIC_RELAXED, __HIP_MEMORY_SCOPE_AGENT);
    }
    if (tid < 12){ lds_c[tid] = 0.f; lds_hout[tid] = 0.f; }

    // ---------------- persistent weight load (once) ----------------
    uint32_t w0[3][14];    // L0: 2 x-chunks (W_ih0) + 12 h-chunks (W_hh0), packed bf16
    uint32_t w1r[3][16];   // L1: chunks 8..11 (W_ih1) + 12..23 (W_hh1)

    if (fp32in){
        const float2* Wih0f = (const float2*)Wih0_;
        const float2* Whh0f = (const float2*)Whh0_;
        const float2* Wih1f = (const float2*)Wih1_;
        const float2* Whh1f = (const float2*)Whh1_;
        #pragma unroll
        for (int j = 0; j < 3; ++j){
            const int rr = w*3 + j;
            const int grow = (rr & 3)*HDIM + g*UPW + (rr >> 2);
            float2 t;
            t = Wih0f[grow*(DIN/2) + l];        w0[j][0] = packbf(t.x, t.y);
            t = Wih0f[grow*(DIN/2) + 64 + l];   w0[j][1] = packbf(t.x, t.y);
            #pragma unroll
            for (int c = 2; c < 14; ++c){
                t = Whh0f[grow*(HDIM/2) + (c-2)*64 + l]; w0[j][c] = packbf(t.x, t.y);
            }
            #pragma unroll
            for (int c = 0; c < 8; ++c){
                t = Wih1f[grow*(HDIM/2) + c*64 + l];
                lds_w[((w*3 + j)*8 + c)*64 + l] = packbf(t.x, t.y);
            }
            #pragma unroll
            for (int c = 8; c < 12; ++c){
                t = Wih1f[grow*(HDIM/2) + c*64 + l]; w1r[j][c-8] = packbf(t.x, t.y);
            }
            #pragma unroll
            for (int c = 12; c < 24; ++c){
                t = Whh1f[grow*(HDIM/2) + (c-12)*64 + l]; w1r[j][c-8] = packbf(t.x, t.y);
            }
        }
    } else {
        const uint32_t* Wih0p = (const uint32_t*)Wih0_;
        const uint32_t* Whh0p = (const uint32_t*)Whh0_;
        const uint32_t* Wih1p = (const uint32_t*)Wih1_;
        const uint32_t* Whh1p = (const uint32_t*)Whh1_;
        #pragma unroll
        for (int j = 0; j < 3; ++j){
            const int rr = w*3 + j;
            const int grow = (rr & 3)*HDIM + g*UPW + (rr >> 2);
            w0[j][0] = Wih0p[grow*(DIN/2) + l];
            w0[j][1] = Wih0p[grow*(DIN/2) + 64 + l];
            #pragma unroll
            for (int c = 2; c < 14; ++c)
                w0[j][c] = Whh0p[grow*(HDIM/2) + (c-2)*64 + l];
            #pragma unroll
            for (int c = 0; c < 8; ++c)
                lds_w[((w*3 + j)*8 + c)*64 + l] = Wih1p[grow*(HDIM/2) + c*64 + l];
            #pragma unroll
            for (int c = 8; c < 12; ++c)
                w1r[j][c-8] = Wih1p[grow*(HDIM/2) + c*64 + l];
            #pragma unroll
            for (int c = 12; c < 24; ++c)
                w1r[j][c-8] = Whh1p[grow*(HDIM/2) + (c-12)*64 + l];
        }
    }

    cg::grid_group grid = cg::this_grid();
    grid.sync();

    // ---------------- sequential phases ----------------
    // phase n computes layer0(t=n) [n<NSTEP] and layer1(t=n-1) [n>=1]
    for (int n = 0; n <= NSTEP; ++n){
        {
            const int nn = (n < NSTEP) ? n : 0;
            const int xbase = ((nn & 15)*64 + (nn >> 4) + 1) * XN;  // batch[b][ei] element offset
            float* h0src = wsf + WS_H0 + ((n+1) & 1)*HDIM;          // h0(n-1)
            float* h1src = wsf + WS_H1 + (n & 1)*HDIM;              // h1(n-2)
            for (int idx = tid; idx < STAGE_N; idx += TPB){
                float v;
                if (idx < XN)
                    v = fp32in ? ((const float*)batch_)[xbase + idx]
                               : bf2f(((const uint16_t*)batch_)[xbase + idx]);
                else if (idx < SGH1)
                    v = __hip_atomic_load(&h0src[idx - XN],
                                          __ATOMIC_RELAXED, __HIP_MEMORY_SCOPE_AGENT);
                else
                    v = __hip_atomic_load(&h1src[idx - SGH1],
                                          __ATOMIC_RELAXED, __HIP_MEMORY_SCOPE_AGENT);
                lds_stage[idx] = v;
            }
        }
        __syncthreads();

        // per-lane register copies of x / h slices
        float xf[4], h0f[24], h1f[24];
        {
            xf[0] = lds_stage[2*l];       xf[1] = lds_stage[2*l + 1];
            xf[2] = lds_stage[128 + 2*l]; xf[3] = lds_stage[128 + 2*l + 1];
            #pragma unroll
            for (int k = 0; k < 12; ++k){
                h0f[2*k]   = lds_stage[SGH0 + 2*(k*64 + l)];
                h0f[2*k+1] = lds_stage[SGH0 + 2*(k*64 + l) + 1];
            }
            #pragma unroll
            for (int k = 0; k < 12; ++k){
                h1f[2*k]   = lds_stage[SGH1 + 2*(k*64 + l)];
                h1f[2*k+1] = lds_stage[SGH1 + 2*(k*64 + l) + 1];
            }
        }

        // dot products
        float acc0[3], acc1[3];
        #pragma unroll
        for (int j = 0; j < 3; ++j){
            float a = 0.f;
            a = fmaf(bflo(w0[j][0]), xf[0], a);
            a = fmaf(bfhi(w0[j][0]), xf[1], a);
            a = fmaf(bflo(w0[j][1]), xf[2], a);
            a = fmaf(bfhi(w0[j][1]), xf[3], a);
            #pragma unroll
            for (int c = 2; c < 14; ++c){
                a = fmaf(bflo(w0[j][c]), h0f[2*(c-2)],   a);
                a = fmaf(bfhi(w0[j][c]), h0f[2*(c-2)+1], a);
            }
            acc0[j] = a;
        }
        #pragma unroll
        for (int j = 0; j < 3; ++j){
            float a = 0.f;
            #pragma unroll
            for (int c = 0; c < 8; ++c){
                const uint32_t p = lds_w[((w*3 + j)*8 + c)*64 + l];
                a = fmaf(bflo(p), h0f[2*c],   a);
                a = fmaf(bfhi(p), h0f[2*c+1], a);
            }
            #pragma unroll
            for (int c = 8; c < 12; ++c){
                const uint32_t p = w1r[j][c-8];
                a = fmaf(bflo(p), h0f[2*c],   a);
                a = fmaf(bfhi(p), h0f[2*c+1], a);
            }
            #pragma unroll
            for (int c = 12; c < 24; ++c){
                const uint32_t p = w1r[j][c-8];
                a = fmaf(bflo(p), h1f[2*(c-12)],   a);
                a = fmaf(bfhi(p), h1f[2*(c-12)+1], a);
            }
            acc1[j] = a;
        }
        #pragma unroll
        for (int j = 0; j < 3; ++j){
            const float r0 = wave_sum(acc0[j]);
            const float r1 = wave_sum(acc1[j]);
            if (l == 0){
                lds_pre[w*3 + j]      = r0;
                lds_pre[24 + w*3 + j] = r1;
            }
        }
        __syncthreads();

        // cell updates: threads 0..5 = layer0 units, 6..11 = layer1 units
        if (tid < 12){
            const int layer = tid / 6, uu = tid % 6;
            const bool active = (layer == 0) ? (n < NSTEP) : (n >= 1);
            if (active){
                const float* pre = &lds_pre[layer*24 + uu*4];
                const float* bb  = &lds_b[layer*24 + uu*4];
                const float gi = pre[0] + bb[0];
                const float gf = pre[1] + bb[1];
                const float gg = pre[2] + bb[2];
                const float go = pre[3] + bb[3];
                const float si = 1.f/(1.f + __expf(-gi));
                const float sf = 1.f/(1.f + __expf(-gf));
                const float so = 1.f/(1.f + __expf(-go));
                const float cn = sf*lds_c[tid] + si*tanhf(gg);
                lds_c[tid] = cn;
                lds_hout[tid] = so * tanhf(cn);
            }
        }
        __syncthreads();

        // publish h0(n) and h1(n-1) (fp32, agent scope)
        if (tid < 6){
            __hip_atomic_store(&wsf[WS_H0 + (n & 1)*HDIM + g*UPW + tid], lds_hout[tid],
                               __ATOMIC_RELAXED, __HIP_MEMORY_SCOPE_AGENT);
        } else if (tid < 12){
            __hip_atomic_store(&wsf[WS_H1 + ((n+1) & 1)*HDIM + g*UPW + (tid-6)], lds_hout[tid],
                               __ATOMIC_RELAXED, __HIP_MEMORY_SCOPE_AGENT);
        }
        grid.sync();
    }

    // ---------------- output: h[2][1536] ++ c[2][1536] ----------------
    if (tid < 12){
        const int layer = tid / 6, uu = tid % 6;
        const int oi = layer*HDIM + g*UPW + uu;
        if (fp32in){
            ((float*)out_)[oi]        = lds_hout[tid];
            ((float*)out_)[3072 + oi] = lds_c[tid];
        } else {
            ((uint16_t*)out_)[oi]        = f2bf(lds_hout[tid]);
            ((uint16_t*)out_)[3072 + oi] = f2bf(lds_c[tid]);
        }
    }
}

extern "C" void kernel_launch(void* const* d_in, const int* in_sizes, int n_in,
                              void* d_out, int out_size, void* d_ws, size_t ws_size,
                              hipStream_t stream)
{
    (void)in_sizes; (void)n_in; (void)out_size; (void)ws_size;
    const void* batch = d_in[0];
    const void* Wih0  = d_in[1];
    const void* Whh0  = d_in[2];
    const void* bih0  = d_in[3];
    const void* bhh0  = d_in[4];
    const void* Wih1  = d_in[5];
    const void* Whh1  = d_in[6];
    const void* bih1  = d_in[7];
    const void* bhh1  = d_in[8];
    void* out = d_out;
    uint32_t* ws = (uint32_t*)d_ws;

    hipLaunchKernelGGL(dtype_probe, dim3(1), dim3(64), 0, stream,
                       (const uint32_t*)Whh0, ws);

    void* args[] = { &batch, &Wih0, &Whh0, &bih0, &bhh0,
                     &Wih1, &Whh1, &bih1, &bhh1, &out, &ws };
    hipLaunchCooperativeKernel((const void*)lstm_seq_kernel,
                               dim3(NWG), dim3(TPB), args, 0, stream);
}

// Round 3
// 10443.330 us; speedup vs baseline: 2.8493x; 2.8493x over previous
//
#include <hip/hip_runtime.h>
#include <cstdint>

#define HDIM   1536
#define DIN    256
#define NSTEP  1008     // (T-1)*B = 63*16
#define NWG    256
#define TPB    512
#define UPW    6        // hidden units per WG per layer (256*6 = 1536)

#define XN      256                 // x elements per step
#define SGH0    XN                  // stage offset of h0
#define SGH1    (XN + HDIM)         // stage offset of h1
#define STAGE_N (XN + 2*HDIM)       // 3328 floats

// ws layout (32-bit words):
//   [0    .. 3071]  h0 exchange, fp32, [2 parities][1536]
//   [3072 .. 6143]  h1 exchange, fp32, [2 parities][1536]
//   [6144]          dtype flag: 1 = fp32 inputs, 0 = bf16 inputs
//   [6208 .. )      barrier sub-counters: [NBAR][16]  (64B line per barrier)
//   [22400 .. )     barrier root counters: [NBAR]
#define WS_H0   0
#define WS_H1   3072
#define WS_FLAG 6144
#define WS_SUB  6208
#define NBAR    1009            // 1 init + 1008 phase barriers
#define WS_ROOT 22400

__device__ __forceinline__ float bflo(uint32_t p){ union{uint32_t u; float f;} v; v.u = p << 16; return v.f; }
__device__ __forceinline__ float bfhi(uint32_t p){ union{uint32_t u; float f;} v; v.u = p & 0xffff0000u; return v.f; }
__device__ __forceinline__ float bf2f(uint16_t b){ union{uint32_t u; float f;} v; v.u = ((uint32_t)b) << 16; return v.f; }
__device__ __forceinline__ uint16_t f2bf(float f){
    union{float f; uint32_t u;} v; v.f = f;
    uint32_t r = v.u + 0x7fffu + ((v.u >> 16) & 1u);   // RNE
    return (uint16_t)(r >> 16);
}
__device__ __forceinline__ uint32_t packbf(float lo, float hi){
    return (uint32_t)f2bf(lo) | ((uint32_t)f2bf(hi) << 16);
}

// sum across all 64 lanes, result in every lane
__device__ __forceinline__ float wave_sum(float x){
    #pragma unroll
    for (int o = 1; o < 64; o <<= 1) x += __shfl_xor(x, o, 64);
    return x;
}

// ---------------------------------------------------------------------------
// init kernel: zero barrier counters + dtype probe (first 256 words of W_hh0;
// bf16-packed data has the low-16 "exponent" concentrated in the Gaussian
// window, fp32 mantissa bits are uniform).
// ---------------------------------------------------------------------------
__global__ void init_ws(const uint32_t* __restrict__ w, uint32_t* __restrict__ ws){
    const int i = blockIdx.x * blockDim.x + threadIdx.x;
    if (i < 16*NBAR) ws[WS_SUB + i]  = 0u;
    if (i < NBAR)    ws[WS_ROOT + i] = 0u;
    if (blockIdx.x == 0 && threadIdx.x < 64){
        const int t = threadIdx.x;
        int cnt = 0;
        #pragma unroll
        for (int j = 0; j < 4; ++j){
            const uint32_t v = w[t*4 + j];
            const uint32_t e = (v >> 7) & 0xFFu;
            if (e == 0u || (e >= 0x70u && e <= 0x7Cu)) cnt++;
        }
        #pragma unroll
        for (int o = 1; o < 64; o <<= 1) cnt += __shfl_xor(cnt, o, 64);
        if (t == 0)
            ws[WS_FLAG] = (cnt < 128) ? 1u : 0u;   // sparse in-window => fp32
    }
}

// two-level grid barrier; counters pre-zeroed per barrier index (no reset).
// Assumes caller's prior global stores are drained (the preceding
// __syncthreads emits s_waitcnt vmcnt(0)).
__device__ __forceinline__ void grid_barrier(uint32_t* __restrict__ ws,
                                             int idx, int g, int tid){
    __syncthreads();    // drains vmcnt: all this WG's publish stores complete
    if (tid == 0){
        uint32_t* sub  = ws + WS_SUB + idx*16 + (g & 15);
        uint32_t* root = ws + WS_ROOT + idx;
        const uint32_t o = __hip_atomic_fetch_add(sub, 1u,
                              __ATOMIC_ACQ_REL, __HIP_MEMORY_SCOPE_AGENT);
        if (o == 15u)
            __hip_atomic_fetch_add(root, 1u,
                              __ATOMIC_RELEASE, __HIP_MEMORY_SCOPE_AGENT);
        while (__hip_atomic_load(root, __ATOMIC_RELAXED,
                                 __HIP_MEMORY_SCOPE_AGENT) != 16u)
            __builtin_amdgcn_s_sleep(1);
    }
    __syncthreads();
}

__global__ __launch_bounds__(TPB, 2)
void lstm_seq_kernel(const void* __restrict__ batch_,
                     const void* __restrict__ Wih0_,
                     const void* __restrict__ Whh0_,
                     const void* __restrict__ bih0_,
                     const void* __restrict__ bhh0_,
                     const void* __restrict__ Wih1_,
                     const void* __restrict__ Whh1_,
                     const void* __restrict__ bih1_,
                     const void* __restrict__ bhh1_,
                     void* __restrict__ out_,
                     uint32_t* __restrict__ ws)
{
    __shared__ uint32_t lds_w[8*3*8*64];     // L1 rows, h0-chunks 0..7 (packed bf16)
    __shared__ float    lds_stage[STAGE_N];  // x ++ h0 ++ h1 (fp32)
    __shared__ float    lds_pre[48];         // 24 L0 + 24 L1 pre-activations
    __shared__ float    lds_b[48];           // fused biases
    __shared__ float    lds_c[12];           // c-state
    __shared__ float    lds_hout[12];        // h-state (fp32)

    const int g   = blockIdx.x;
    const int tid = threadIdx.x;
    const int w   = tid >> 6;
    const int l   = tid & 63;

    const uint32_t fp32in = __hip_atomic_load(&ws[WS_FLAG],
                             __ATOMIC_RELAXED, __HIP_MEMORY_SCOPE_AGENT);
    float* wsf = (float*)ws;

    // ---------------- init ----------------
    if (tid < 24){
        const int uu = tid >> 2, gate = tid & 3;
        const int grow = gate*HDIM + g*UPW + uu;
        if (fp32in){
            lds_b[tid]      = ((const float*)bih0_)[grow] + ((const float*)bhh0_)[grow];
            lds_b[24 + tid] = ((const float*)bih1_)[grow] + ((const float*)bhh1_)[grow];
        } else {
            lds_b[tid]      = bf2f(((const uint16_t*)bih0_)[grow]) + bf2f(((const uint16_t*)bhh0_)[grow]);
            lds_b[24 + tid] = bf2f(((const uint16_t*)bih1_)[grow]) + bf2f(((const uint16_t*)bhh1_)[grow]);
        }
        // zero own h-exchange slots in all 4 buffers (layer x parity)
        const int layer = tid / 12, rem = tid % 12;
        const int par = rem / 6, k = rem % 6;
        __hip_atomic_store(&wsf[(layer ? WS_H1 : WS_H0) + par*HDIM + g*UPW + k], 0.0f,
                           __ATOMIC_RELAXED, __HIP_MEMORY_SCOPE_AGENT);
    }
    if (tid < 12){ lds_c[tid] = 0.f; lds_hout[tid] = 0.f; }

    // ---------------- persistent weight load (once) ----------------
    uint32_t w0[3][14];    // L0: 2 x-chunks (W_ih0) + 12 h-chunks (W_hh0), packed bf16
    uint32_t w1r[3][16];   // L1: chunks 8..11 (W_ih1) + 12..23 (W_hh1)

    if (fp32in){
        const float2* Wih0f = (const float2*)Wih0_;
        const float2* Whh0f = (const float2*)Whh0_;
        const float2* Wih1f = (const float2*)Wih1_;
        const float2* Whh1f = (const float2*)Whh1_;
        #pragma unroll
        for (int j = 0; j < 3; ++j){
            const int rr = w*3 + j;
            const int grow = (rr & 3)*HDIM + g*UPW + (rr >> 2);
            float2 t;
            t = Wih0f[grow*(DIN/2) + l];        w0[j][0] = packbf(t.x, t.y);
            t = Wih0f[grow*(DIN/2) + 64 + l];   w0[j][1] = packbf(t.x, t.y);
            #pragma unroll
            for (int c = 2; c < 14; ++c){
                t = Whh0f[grow*(HDIM/2) + (c-2)*64 + l]; w0[j][c] = packbf(t.x, t.y);
            }
            #pragma unroll
            for (int c = 0; c < 8; ++c){
                t = Wih1f[grow*(HDIM/2) + c*64 + l];
                lds_w[((w*3 + j)*8 + c)*64 + l] = packbf(t.x, t.y);
            }
            #pragma unroll
            for (int c = 8; c < 12; ++c){
                t = Wih1f[grow*(HDIM/2) + c*64 + l]; w1r[j][c-8] = packbf(t.x, t.y);
            }
            #pragma unroll
            for (int c = 12; c < 24; ++c){
                t = Whh1f[grow*(HDIM/2) + (c-12)*64 + l]; w1r[j][c-8] = packbf(t.x, t.y);
            }
        }
    } else {
        const uint32_t* Wih0p = (const uint32_t*)Wih0_;
        const uint32_t* Whh0p = (const uint32_t*)Whh0_;
        const uint32_t* Wih1p = (const uint32_t*)Wih1_;
        const uint32_t* Whh1p = (const uint32_t*)Whh1_;
        #pragma unroll
        for (int j = 0; j < 3; ++j){
            const int rr = w*3 + j;
            const int grow = (rr & 3)*HDIM + g*UPW + (rr >> 2);
            w0[j][0] = Wih0p[grow*(DIN/2) + l];
            w0[j][1] = Wih0p[grow*(DIN/2) + 64 + l];
            #pragma unroll
            for (int c = 2; c < 14; ++c)
                w0[j][c] = Whh0p[grow*(HDIM/2) + (c-2)*64 + l];
            #pragma unroll
            for (int c = 0; c < 8; ++c)
                lds_w[((w*3 + j)*8 + c)*64 + l] = Wih1p[grow*(HDIM/2) + c*64 + l];
            #pragma unroll
            for (int c = 8; c < 12; ++c)
                w1r[j][c-8] = Wih1p[grow*(HDIM/2) + c*64 + l];
            #pragma unroll
            for (int c = 12; c < 24; ++c)
                w1r[j][c-8] = Whh1p[grow*(HDIM/2) + (c-12)*64 + l];
        }
    }

    grid_barrier(ws, 0, g, tid);

    // ---------------- sequential phases ----------------
    // phase n computes layer0(t=n) [n<NSTEP] and layer1(t=n-1) [n>=1]
    for (int n = 0; n <= NSTEP; ++n){
        // stage x(n), h0(n-1), h1(n-2) into LDS (loads pipelined via regs)
        {
            float* h0src = wsf + WS_H0 + ((n+1) & 1)*HDIM;  // h0(n-1)
            float* h1src = wsf + WS_H1 + (n & 1)*HDIM;      // h1(n-2)
            float tmp[6];
            #pragma unroll
            for (int j = 0; j < 3; ++j)
                tmp[j] = __hip_atomic_load(&h0src[tid + j*TPB],
                                           __ATOMIC_RELAXED, __HIP_MEMORY_SCOPE_AGENT);
            #pragma unroll
            for (int j = 0; j < 3; ++j)
                tmp[3+j] = __hip_atomic_load(&h1src[tid + j*TPB],
                                           __ATOMIC_RELAXED, __HIP_MEMORY_SCOPE_AGENT);
            if (tid < XN){
                const int nn = (n < NSTEP) ? n : 0;
                const int xbase = ((nn & 15)*64 + (nn >> 4) + 1) * XN;  // batch[b][ei]
                lds_stage[tid] = fp32in ? ((const float*)batch_)[xbase + tid]
                                        : bf2f(((const uint16_t*)batch_)[xbase + tid]);
            }
            #pragma unroll
            for (int j = 0; j < 3; ++j)
                lds_stage[SGH0 + tid + j*TPB] = tmp[j];
            #pragma unroll
            for (int j = 0; j < 3; ++j)
                lds_stage[SGH1 + tid + j*TPB] = tmp[3+j];
        }
        __syncthreads();

        // per-lane register copies of x / h slices
        float xf[4], h0f[24], h1f[24];
        {
            xf[0] = lds_stage[2*l];       xf[1] = lds_stage[2*l + 1];
            xf[2] = lds_stage[128 + 2*l]; xf[3] = lds_stage[128 + 2*l + 1];
            #pragma unroll
            for (int k = 0; k < 12; ++k){
                h0f[2*k]   = lds_stage[SGH0 + 2*(k*64 + l)];
                h0f[2*k+1] = lds_stage[SGH0 + 2*(k*64 + l) + 1];
            }
            #pragma unroll
            for (int k = 0; k < 12; ++k){
                h1f[2*k]   = lds_stage[SGH1 + 2*(k*64 + l)];
                h1f[2*k+1] = lds_stage[SGH1 + 2*(k*64 + l) + 1];
            }
        }

        // dot products
        float acc0[3], acc1[3];
        #pragma unroll
        for (int j = 0; j < 3; ++j){
            float a = 0.f;
            a = fmaf(bflo(w0[j][0]), xf[0], a);
            a = fmaf(bfhi(w0[j][0]), xf[1], a);
            a = fmaf(bflo(w0[j][1]), xf[2], a);
            a = fmaf(bfhi(w0[j][1]), xf[3], a);
            #pragma unroll
            for (int c = 2; c < 14; ++c){
                a = fmaf(bflo(w0[j][c]), h0f[2*(c-2)],   a);
                a = fmaf(bfhi(w0[j][c]), h0f[2*(c-2)+1], a);
            }
            acc0[j] = a;
        }
        #pragma unroll
        for (int j = 0; j < 3; ++j){
            float a = 0.f;
            #pragma unroll
            for (int c = 0; c < 8; ++c){
                const uint32_t p = lds_w[((w*3 + j)*8 + c)*64 + l];
                a = fmaf(bflo(p), h0f[2*c],   a);
                a = fmaf(bfhi(p), h0f[2*c+1], a);
            }
            #pragma unroll
            for (int c = 8; c < 12; ++c){
                const uint32_t p = w1r[j][c-8];
                a = fmaf(bflo(p), h0f[2*c],   a);
                a = fmaf(bfhi(p), h0f[2*c+1], a);
            }
            #pragma unroll
            for (int c = 12; c < 24; ++c){
                const uint32_t p = w1r[j][c-8];
                a = fmaf(bflo(p), h1f[2*(c-12)],   a);
                a = fmaf(bfhi(p), h1f[2*(c-12)+1], a);
            }
            acc1[j] = a;
        }
        #pragma unroll
        for (int j = 0; j < 3; ++j){
            const float r0 = wave_sum(acc0[j]);
            const float r1 = wave_sum(acc1[j]);
            if (l == 0){
                lds_pre[w*3 + j]      = r0;
                lds_pre[24 + w*3 + j] = r1;
            }
        }
        __syncthreads();

        // cell updates + immediate publish: threads 0..5 = L0 units, 6..11 = L1
        if (tid < 12){
            const int layer = tid / 6, uu = tid % 6;
            const bool active = (layer == 0) ? (n < NSTEP) : (n >= 1);
            if (active){
                const float* pre = &lds_pre[layer*24 + uu*4];
                const float* bb  = &lds_b[layer*24 + uu*4];
                const float gi = pre[0] + bb[0];
                const float gf = pre[1] + bb[1];
                const float gg = pre[2] + bb[2];
                const float go = pre[3] + bb[3];
                const float si = 1.f/(1.f + __expf(-gi));
                const float sf = 1.f/(1.f + __expf(-gf));
                const float so = 1.f/(1.f + __expf(-go));
                const float cn = sf*lds_c[tid] + si*tanhf(gg);
                const float hn = so * tanhf(cn);
                lds_c[tid] = cn;
                lds_hout[tid] = hn;
                if (layer == 0){
                    // h0(n), parity n&1 — consumed at phase n+1
                    __hip_atomic_store(&wsf[WS_H0 + (n & 1)*HDIM + g*UPW + uu], hn,
                                       __ATOMIC_RELAXED, __HIP_MEMORY_SCOPE_AGENT);
                } else if (n < NSTEP){
                    // h1(n-1), parity (n+1)&1 — consumed at phase n+1
                    __hip_atomic_store(&wsf[WS_H1 + ((n+1) & 1)*HDIM + g*UPW + uu], hn,
                                       __ATOMIC_RELAXED, __HIP_MEMORY_SCOPE_AGENT);
                }
            }
        }

        if (n < NSTEP)
            grid_barrier(ws, n + 1, g, tid);
    }

    // ---------------- output: h[2][1536] ++ c[2][1536] ----------------
    if (tid < 12){
        const int layer = tid / 6, uu = tid % 6;
        const int oi = layer*HDIM + g*UPW + uu;
        if (fp32in){
            ((float*)out_)[oi]        = lds_hout[tid];
            ((float*)out_)[3072 + oi] = lds_c[tid];
        } else {
            ((uint16_t*)out_)[oi]        = f2bf(lds_hout[tid]);
            ((uint16_t*)out_)[3072 + oi] = f2bf(lds_c[tid]);
        }
    }
}

extern "C" void kernel_launch(void* const* d_in, const int* in_sizes, int n_in,
                              void* d_out, int out_size, void* d_ws, size_t ws_size,
                              hipStream_t stream)
{
    (void)in_sizes; (void)n_in; (void)out_size; (void)ws_size;
    const void* batch = d_in[0];
    const void* Wih0  = d_in[1];
    const void* Whh0  = d_in[2];
    const void* bih0  = d_in[3];
    const void* bhh0  = d_in[4];
    const void* Wih1  = d_in[5];
    const void* Whh1  = d_in[6];
    const void* bih1  = d_in[7];
    const void* bhh1  = d_in[8];
    void* out = d_out;
    uint32_t* ws = (uint32_t*)d_ws;

    hipLaunchKernelGGL(init_ws, dim3((16*NBAR + 1023)/1024), dim3(1024), 0, stream,
                       (const uint32_t*)Whh0, ws);

    void* args[] = { &batch, &Wih0, &Whh0, &bih0, &bhh0,
                     &Wih1, &Whh1, &bih1, &bhh1, &out, &ws };
    hipLaunchCooperativeKernel((const void*)lstm_seq_kernel,
                               dim3(NWG), dim3(TPB), args, 0, stream);
}

// Round 4
// 7119.168 us; speedup vs baseline: 4.1798x; 1.4669x over previous
//
#include <hip/hip_runtime.h>
#include <cstdint>

#define HDIM   1536
#define DIN    256
#define NSTEP  1008     // (T-1)*B = 63*16
#define NWG    256
#define TPB    512
#define UPW    6        // hidden units per WG per layer (256*6 = 1536)

#define XN      256                 // x elements per step
#define SGH0    XN                  // stage offset of h0
#define SGH1    (XN + HDIM)         // stage offset of h1
#define STAGE_N (XN + 2*HDIM)       // 3328 floats

// ws layout:
//   u64 [0     .. 3071]  h0 chunks {fp32,tag}, [2 parities][1536]
//   u64 [3072  .. 6143]  h1 chunks {fp32,tag}, [2 parities][1536]
//   u32 [12288]          dtype flag: 1 = fp32 inputs, 0 = bf16 inputs
// Producer at phase p: h0(p) -> parity p&1, tag p+1 ; h1(p-1) -> parity (p+1)&1, tag p+1.
// Consumer at phase n wants tag n on h0 parity (n+1)&1 and h1 parity n&1.
#define CH_H0    0
#define CH_H1    3072
#define WS_FLAG_W 12288

__device__ __forceinline__ float bflo(uint32_t p){ union{uint32_t u; float f;} v; v.u = p << 16; return v.f; }
__device__ __forceinline__ float bfhi(uint32_t p){ union{uint32_t u; float f;} v; v.u = p & 0xffff0000u; return v.f; }
__device__ __forceinline__ float bf2f(uint16_t b){ union{uint32_t u; float f;} v; v.u = ((uint32_t)b) << 16; return v.f; }
__device__ __forceinline__ uint16_t f2bf(float f){
    union{float f; uint32_t u;} v; v.f = f;
    uint32_t r = v.u + 0x7fffu + ((v.u >> 16) & 1u);   // RNE
    return (uint16_t)(r >> 16);
}
__device__ __forceinline__ uint32_t packbf(float lo, float hi){
    return (uint32_t)f2bf(lo) | ((uint32_t)f2bf(hi) << 16);
}
__device__ __forceinline__ uint64_t pack_ht(float h, uint32_t tag){
    union{float f; uint32_t u;} v; v.f = h;
    return (uint64_t)v.u | ((uint64_t)tag << 32);
}
__device__ __forceinline__ float chunk_val(uint64_t c){
    union{uint32_t u; float f;} v; v.u = (uint32_t)c; return v.f;
}

// sum across all 64 lanes, result in every lane
__device__ __forceinline__ float wave_sum(float x){
    #pragma unroll
    for (int o = 1; o < 64; o <<= 1) x += __shfl_xor(x, o, 64);
    return x;
}

// ---------------------------------------------------------------------------
// init kernel: seed boot chunks (initial zero h-state with tags) + dtype probe
// (first 256 words of W_hh0: bf16-packed data has low-16 "exponent" in the
// Gaussian window; fp32 mantissa bits are uniform there).
// ---------------------------------------------------------------------------
__global__ void init_ws(const uint32_t* __restrict__ w, uint32_t* __restrict__ ws){
    uint64_t* ws64 = (uint64_t*)ws;
    const int i = blockIdx.x * blockDim.x + threadIdx.x;
    if (i < HDIM){
        ws64[CH_H0 + 1*HDIM + i] = 0ull;                 // h0(-1): parity 1, tag 0, val 0
        ws64[CH_H1 + 0*HDIM + i] = 0ull;                 // h1(-2): parity 0, tag 0, val 0
        ws64[CH_H1 + 1*HDIM + i] = ((uint64_t)1 << 32);  // h1(-1): parity 1, tag 1, val 0
    }
    if (blockIdx.x == 0 && threadIdx.x < 64){
        const int t = threadIdx.x;
        int cnt = 0;
        #pragma unroll
        for (int j = 0; j < 4; ++j){
            const uint32_t v = w[t*4 + j];
            const uint32_t e = (v >> 7) & 0xFFu;
            if (e == 0u || (e >= 0x70u && e <= 0x7Cu)) cnt++;
        }
        #pragma unroll
        for (int o = 1; o < 64; o <<= 1) cnt += __shfl_xor(cnt, o, 64);
        if (t == 0)
            ws[WS_FLAG_W] = (cnt < 128) ? 1u : 0u;   // sparse in-window => fp32
    }
}

__global__ __launch_bounds__(TPB, 2)
void lstm_seq_kernel(const void* __restrict__ batch_,
                     const void* __restrict__ Wih0_,
                     const void* __restrict__ Whh0_,
                     const void* __restrict__ bih0_,
                     const void* __restrict__ bhh0_,
                     const void* __restrict__ Wih1_,
                     const void* __restrict__ Whh1_,
                     const void* __restrict__ bih1_,
                     const void* __restrict__ bhh1_,
                     void* __restrict__ out_,
                     uint32_t* __restrict__ ws)
{
    __shared__ uint32_t lds_w[8*3*8*64];     // L1 rows, h0-chunks 0..7 (packed bf16)
    __shared__ float    lds_stage[STAGE_N];  // x ++ h0 ++ h1 (fp32)
    __shared__ float    lds_pre[48];         // 24 L0 + 24 L1 pre-activations
    __shared__ float    lds_b[48];           // fused biases
    __shared__ float    lds_c[12];           // c-state
    __shared__ float    lds_hout[12];        // h-state (fp32)

    const int g   = blockIdx.x;
    const int tid = threadIdx.x;
    const int w   = tid >> 6;
    const int l   = tid & 63;

    const uint32_t fp32in = __hip_atomic_load(&ws[WS_FLAG_W],
                             __ATOMIC_RELAXED, __HIP_MEMORY_SCOPE_AGENT);
    uint64_t* ws64 = (uint64_t*)ws;

    // ---------------- init ----------------
    if (tid < 24){
        const int uu = tid >> 2, gate = tid & 3;
        const int grow = gate*HDIM + g*UPW + uu;
        if (fp32in){
            lds_b[tid]      = ((const float*)bih0_)[grow] + ((const float*)bhh0_)[grow];
            lds_b[24 + tid] = ((const float*)bih1_)[grow] + ((const float*)bhh1_)[grow];
        } else {
            lds_b[tid]      = bf2f(((const uint16_t*)bih0_)[grow]) + bf2f(((const uint16_t*)bhh0_)[grow]);
            lds_b[24 + tid] = bf2f(((const uint16_t*)bih1_)[grow]) + bf2f(((const uint16_t*)bhh1_)[grow]);
        }
    }
    if (tid < 12){ lds_c[tid] = 0.f; lds_hout[tid] = 0.f; }

    // ---------------- persistent weight load (once) ----------------
    uint32_t w0[3][14];    // L0: 2 x-chunks (W_ih0) + 12 h-chunks (W_hh0), packed bf16
    uint32_t w1r[3][16];   // L1: chunks 8..11 (W_ih1) + 12..23 (W_hh1)

    if (fp32in){
        const float2* Wih0f = (const float2*)Wih0_;
        const float2* Whh0f = (const float2*)Whh0_;
        const float2* Wih1f = (const float2*)Wih1_;
        const float2* Whh1f = (const float2*)Whh1_;
        #pragma unroll
        for (int j = 0; j < 3; ++j){
            const int rr = w*3 + j;
            const int grow = (rr & 3)*HDIM + g*UPW + (rr >> 2);
            float2 t;
            t = Wih0f[grow*(DIN/2) + l];        w0[j][0] = packbf(t.x, t.y);
            t = Wih0f[grow*(DIN/2) + 64 + l];   w0[j][1] = packbf(t.x, t.y);
            #pragma unroll
            for (int c = 2; c < 14; ++c){
                t = Whh0f[grow*(HDIM/2) + (c-2)*64 + l]; w0[j][c] = packbf(t.x, t.y);
            }
            #pragma unroll
            for (int c = 0; c < 8; ++c){
                t = Wih1f[grow*(HDIM/2) + c*64 + l];
                lds_w[((w*3 + j)*8 + c)*64 + l] = packbf(t.x, t.y);
            }
            #pragma unroll
            for (int c = 8; c < 12; ++c){
                t = Wih1f[grow*(HDIM/2) + c*64 + l]; w1r[j][c-8] = packbf(t.x, t.y);
            }
            #pragma unroll
            for (int c = 12; c < 24; ++c){
                t = Whh1f[grow*(HDIM/2) + (c-12)*64 + l]; w1r[j][c-8] = packbf(t.x, t.y);
            }
        }
    } else {
        const uint32_t* Wih0p = (const uint32_t*)Wih0_;
        const uint32_t* Whh0p = (const uint32_t*)Whh0_;
        const uint32_t* Wih1p = (const uint32_t*)Wih1_;
        const uint32_t* Whh1p = (const uint32_t*)Whh1_;
        #pragma unroll
        for (int j = 0; j < 3; ++j){
            const int rr = w*3 + j;
            const int grow = (rr & 3)*HDIM + g*UPW + (rr >> 2);
            w0[j][0] = Wih0p[grow*(DIN/2) + l];
            w0[j][1] = Wih0p[grow*(DIN/2) + 64 + l];
            #pragma unroll
            for (int c = 2; c < 14; ++c)
                w0[j][c] = Whh0p[grow*(HDIM/2) + (c-2)*64 + l];
            #pragma unroll
            for (int c = 0; c < 8; ++c)
                lds_w[((w*3 + j)*8 + c)*64 + l] = Wih1p[grow*(HDIM/2) + c*64 + l];
            #pragma unroll
            for (int c = 8; c < 12; ++c)
                w1r[j][c-8] = Wih1p[grow*(HDIM/2) + c*64 + l];
            #pragma unroll
            for (int c = 12; c < 24; ++c)
                w1r[j][c-8] = Whh1p[grow*(HDIM/2) + (c-12)*64 + l];
        }
    }
    // lds_w consumed only after the first staging __syncthreads below.

    // ---------------- sequential phases ----------------
    // phase n computes layer0(t=n) [n<NSTEP] and layer1(t=n-1) [n>=1]
    for (int n = 0; n <= NSTEP; ++n){
        // x load issued early (independent of h)
        float xv = 0.f;
        if (tid < XN){
            const int nn = (n < NSTEP) ? n : 0;
            const int xbase = ((nn & 15)*64 + (nn >> 4) + 1) * XN;  // batch[b][ei]
            xv = fp32in ? ((const float*)batch_)[xbase + tid]
                        : bf2f(((const uint16_t*)batch_)[xbase + tid]);
        }

        // per-thread spin on 6 tagged chunks (fused barrier + h-load)
        uint64_t v[6];
        {
            const uint64_t* h0c = ws64 + CH_H0 + (((n+1) & 1))*HDIM;  // h0(n-1)
            const uint64_t* h1c = ws64 + CH_H1 + ((n & 1))*HDIM;      // h1(n-2)
            const uint32_t want = (uint32_t)n;
            unsigned pend = 0x3Fu;
            while (pend){
                if (pend & 1u)  v[0] = __hip_atomic_load(&h0c[tid],        __ATOMIC_RELAXED, __HIP_MEMORY_SCOPE_AGENT);
                if (pend & 2u)  v[1] = __hip_atomic_load(&h0c[tid + 512],  __ATOMIC_RELAXED, __HIP_MEMORY_SCOPE_AGENT);
                if (pend & 4u)  v[2] = __hip_atomic_load(&h0c[tid + 1024], __ATOMIC_RELAXED, __HIP_MEMORY_SCOPE_AGENT);
                if (pend & 8u)  v[3] = __hip_atomic_load(&h1c[tid],        __ATOMIC_RELAXED, __HIP_MEMORY_SCOPE_AGENT);
                if (pend & 16u) v[4] = __hip_atomic_load(&h1c[tid + 512],  __ATOMIC_RELAXED, __HIP_MEMORY_SCOPE_AGENT);
                if (pend & 32u) v[5] = __hip_atomic_load(&h1c[tid + 1024], __ATOMIC_RELAXED, __HIP_MEMORY_SCOPE_AGENT);
                unsigned ok = 0;
                #pragma unroll
                for (int j = 0; j < 6; ++j)
                    if ((uint32_t)(v[j] >> 32) == want) ok |= (1u << j);
                pend &= ~ok;
                if (pend) __builtin_amdgcn_s_sleep(1);
            }
        }

        if (tid < XN) lds_stage[tid] = xv;
        #pragma unroll
        for (int j = 0; j < 3; ++j)
            lds_stage[SGH0 + tid + j*TPB] = chunk_val(v[j]);
        #pragma unroll
        for (int j = 0; j < 3; ++j)
            lds_stage[SGH1 + tid + j*TPB] = chunk_val(v[3+j]);
        __syncthreads();

        // per-lane register copies of x / h slices
        float xf[4], h0f[24], h1f[24];
        {
            xf[0] = lds_stage[2*l];       xf[1] = lds_stage[2*l + 1];
            xf[2] = lds_stage[128 + 2*l]; xf[3] = lds_stage[128 + 2*l + 1];
            #pragma unroll
            for (int k = 0; k < 12; ++k){
                h0f[2*k]   = lds_stage[SGH0 + 2*(k*64 + l)];
                h0f[2*k+1] = lds_stage[SGH0 + 2*(k*64 + l) + 1];
            }
            #pragma unroll
            for (int k = 0; k < 12; ++k){
                h1f[2*k]   = lds_stage[SGH1 + 2*(k*64 + l)];
                h1f[2*k+1] = lds_stage[SGH1 + 2*(k*64 + l) + 1];
            }
        }

        // dot products
        float acc0[3], acc1[3];
        #pragma unroll
        for (int j = 0; j < 3; ++j){
            float a = 0.f;
            a = fmaf(bflo(w0[j][0]), xf[0], a);
            a = fmaf(bfhi(w0[j][0]), xf[1], a);
            a = fmaf(bflo(w0[j][1]), xf[2], a);
            a = fmaf(bfhi(w0[j][1]), xf[3], a);
            #pragma unroll
            for (int c = 2; c < 14; ++c){
                a = fmaf(bflo(w0[j][c]), h0f[2*(c-2)],   a);
                a = fmaf(bfhi(w0[j][c]), h0f[2*(c-2)+1], a);
            }
            acc0[j] = a;
        }
        #pragma unroll
        for (int j = 0; j < 3; ++j){
            float a = 0.f;
            #pragma unroll
            for (int c = 0; c < 8; ++c){
                const uint32_t p = lds_w[((w*3 + j)*8 + c)*64 + l];
                a = fmaf(bflo(p), h0f[2*c],   a);
                a = fmaf(bfhi(p), h0f[2*c+1], a);
            }
            #pragma unroll
            for (int c = 8; c < 12; ++c){
                const uint32_t p = w1r[j][c-8];
                a = fmaf(bflo(p), h0f[2*c],   a);
                a = fmaf(bfhi(p), h0f[2*c+1], a);
            }
            #pragma unroll
            for (int c = 12; c < 24; ++c){
                const uint32_t p = w1r[j][c-8];
                a = fmaf(bflo(p), h1f[2*(c-12)],   a);
                a = fmaf(bfhi(p), h1f[2*(c-12)+1], a);
            }
            acc1[j] = a;
        }
        #pragma unroll
        for (int j = 0; j < 3; ++j){
            const float r0 = wave_sum(acc0[j]);
            const float r1 = wave_sum(acc1[j]);
            if (l == 0){
                lds_pre[w*3 + j]      = r0;
                lds_pre[24 + w*3 + j] = r1;
            }
        }
        __syncthreads();

        // cell updates + tagged publish: threads 0..5 = L0 units, 6..11 = L1
        if (tid < 12){
            const int layer = tid / 6, uu = tid % 6;
            const bool active = (layer == 0) ? (n < NSTEP) : (n >= 1);
            if (active){
                const float* pre = &lds_pre[layer*24 + uu*4];
                const float* bb  = &lds_b[layer*24 + uu*4];
                const float gi = pre[0] + bb[0];
                const float gf = pre[1] + bb[1];
                const float gg = pre[2] + bb[2];
                const float go = pre[3] + bb[3];
                const float si = 1.f/(1.f + __expf(-gi));
                const float sf = 1.f/(1.f + __expf(-gf));
                const float so = 1.f/(1.f + __expf(-go));
                const float cn = sf*lds_c[tid] + si*tanhf(gg);
                const float hn = so * tanhf(cn);
                lds_c[tid] = cn;
                lds_hout[tid] = hn;
                const uint64_t pk = pack_ht(hn, (uint32_t)(n + 1));
                if (layer == 0){
                    // h0(n) -> parity n&1, tag n+1 (consumed at phase n+1)
                    __hip_atomic_store(&ws64[CH_H0 + (n & 1)*HDIM + g*UPW + uu], pk,
                                       __ATOMIC_RELAXED, __HIP_MEMORY_SCOPE_AGENT);
                } else {
                    // h1(n-1) -> parity (n+1)&1, tag n+1 (consumed at phase n+1)
                    __hip_atomic_store(&ws64[CH_H1 + ((n+1) & 1)*HDIM + g*UPW + uu], pk,
                                       __ATOMIC_RELAXED, __HIP_MEMORY_SCOPE_AGENT);
                }
            }
        }
        // no barrier: next phase's per-thread tag spin provides the sync
    }

    // ---------------- output: h[2][1536] ++ c[2][1536] ----------------
    if (tid < 12){
        const int layer = tid / 6, uu = tid % 6;
        const int oi = layer*HDIM + g*UPW + uu;
        if (fp32in){
            ((float*)out_)[oi]        = lds_hout[tid];
            ((float*)out_)[3072 + oi] = lds_c[tid];
        } else {
            ((uint16_t*)out_)[oi]        = f2bf(lds_hout[tid]);
            ((uint16_t*)out_)[3072 + oi] = f2bf(lds_c[tid]);
        }
    }
}

extern "C" void kernel_launch(void* const* d_in, const int* in_sizes, int n_in,
                              void* d_out, int out_size, void* d_ws, size_t ws_size,
                              hipStream_t stream)
{
    (void)in_sizes; (void)n_in; (void)out_size; (void)ws_size;
    const void* batch = d_in[0];
    const void* Wih0  = d_in[1];
    const void* Whh0  = d_in[2];
    const void* bih0  = d_in[3];
    const void* bhh0  = d_in[4];
    const void* Wih1  = d_in[5];
    const void* Whh1  = d_in[6];
    const void* bih1  = d_in[7];
    const void* bhh1  = d_in[8];
    void* out = d_out;
    uint32_t* ws = (uint32_t*)d_ws;

    hipLaunchKernelGGL(init_ws, dim3((HDIM + 255)/256), dim3(256), 0, stream,
                       (const uint32_t*)Whh0, ws);

    void* args[] = { &batch, &Wih0, &Whh0, &bih0, &bhh0,
                     &Wih1, &Whh1, &bih1, &bhh1, &out, &ws };
    hipLaunchCooperativeKernel((const void*)lstm_seq_kernel,
                               dim3(NWG), dim3(TPB), args, 0, stream);
}

// Round 5
// 6105.734 us; speedup vs baseline: 4.8735x; 1.1660x over previous
//
#include <hip/hip_runtime.h>
#include <cstdint>

#define HDIM   1536
#define DIN    256
#define NSTEP  1008     // (T-1)*B = 63*16
#define NWG    256
#define TPB    512
#define UPW    6        // hidden units per WG per layer (256*6 = 1536)
#define XN     256      // x elements per step

// u64 chunk = (tag << 32) | (bf16_hi << 16) | bf16_lo   (2 h values + phase tag)
// ws64 layout:
//   [0    .. 1535]  h0 chunks [2 parity][768]
//   [1536 .. 3071]  h1 chunks [2 parity][768]
// u32[6144] = dtype flag (1 = fp32 inputs, 0 = bf16 inputs)
// Producer phase p: h0(p) -> parity p&1, tag p+1 ; h1(p-1) -> parity (p+1)&1, tag p+1.
// Consumer phase n: wants tag n on h0 parity (n+1)&1 and h1 parity n&1.
#define C_H0      0
#define C_H1      1536
#define WS_FLAG_W 6144

__device__ __forceinline__ float bflo(uint32_t p){ union{uint32_t u; float f;} v; v.u = p << 16; return v.f; }
__device__ __forceinline__ float bfhi(uint32_t p){ union{uint32_t u; float f;} v; v.u = p & 0xffff0000u; return v.f; }
__device__ __forceinline__ float bf2f(uint16_t b){ union{uint32_t u; float f;} v; v.u = ((uint32_t)b) << 16; return v.f; }
__device__ __forceinline__ uint16_t f2bf(float f){
    union{float f; uint32_t u;} v; v.f = f;
    uint32_t r = v.u + 0x7fffu + ((v.u >> 16) & 1u);   // RNE
    return (uint16_t)(r >> 16);
}
__device__ __forceinline__ uint32_t packbf(float lo, float hi){
    return (uint32_t)f2bf(lo) | ((uint32_t)f2bf(hi) << 16);
}
// inf-safe fast tanh: 1 - 2/(e^{2x}+1)
__device__ __forceinline__ float tanh_fast(float x){
    return 1.f - 2.f/(__expf(2.f*x) + 1.f);
}

// sum across all 64 lanes, result in every lane
__device__ __forceinline__ float wave_sum(float x){
    #pragma unroll
    for (int o = 1; o < 64; o <<= 1) x += __shfl_xor(x, o, 64);
    return x;
}

// ---------------------------------------------------------------------------
// init kernel: seed boot chunks (zero h-state with boot tags) + dtype probe
// (first 256 words of W_hh0: bf16-packed data has low-16 "exponent" in the
// Gaussian window; fp32 mantissa bits there are uniform).
// ---------------------------------------------------------------------------
__global__ void init_ws(const uint32_t* __restrict__ w, uint32_t* __restrict__ ws){
    uint64_t* ws64 = (uint64_t*)ws;
    const int i = blockIdx.x * blockDim.x + threadIdx.x;
    if (i < 768){
        ws64[C_H0 + 768 + i]  = 0ull;              // h0(-1): parity 1, tag 0, zeros
        ws64[C_H1 + i]        = 0ull;              // h1(-2): parity 0, tag 0, zeros
        ws64[C_H1 + 768 + i]  = ((uint64_t)1 << 32); // h1(-1): parity 1, tag 1, zeros
    }
    if (blockIdx.x == 0 && threadIdx.x < 64){
        const int t = threadIdx.x;
        int cnt = 0;
        #pragma unroll
        for (int j = 0; j < 4; ++j){
            const uint32_t v = w[t*4 + j];
            const uint32_t e = (v >> 7) & 0xFFu;
            if (e == 0u || (e >= 0x70u && e <= 0x7Cu)) cnt++;
        }
        #pragma unroll
        for (int o = 1; o < 64; o <<= 1) cnt += __shfl_xor(cnt, o, 64);
        if (t == 0)
            ws[WS_FLAG_W] = (cnt < 128) ? 1u : 0u;   // sparse in-window => fp32
    }
}

__global__ __launch_bounds__(TPB, 2)
void lstm_seq_kernel(const void* __restrict__ batch_,
                     const void* __restrict__ Wih0_,
                     const void* __restrict__ Whh0_,
                     const void* __restrict__ bih0_,
                     const void* __restrict__ bhh0_,
                     const void* __restrict__ Wih1_,
                     const void* __restrict__ Whh1_,
                     const void* __restrict__ bih1_,
                     const void* __restrict__ bhh1_,
                     void* __restrict__ out_,
                     uint32_t* __restrict__ ws)
{
    __shared__ uint32_t lds_w[8*3*8*64];   // L1 rows, h0-chunks 0..7 (packed bf16)
    __shared__ uint32_t lds_h[1536];       // packed h pairs: [0..767]=h0, [768..1535]=h1
    __shared__ float    lds_pre[48];       // 24 L0 + 24 L1 pre-activations
    __shared__ float    lds_b[48];         // fused biases
    __shared__ float    lds_c[12];         // c-state
    __shared__ float    lds_hout[12];      // h-state (fp32)

    const int g   = blockIdx.x;
    const int tid = threadIdx.x;
    const int w   = tid >> 6;
    const int l   = tid & 63;

    const uint32_t fp32in = __hip_atomic_load(&ws[WS_FLAG_W],
                             __ATOMIC_RELAXED, __HIP_MEMORY_SCOPE_AGENT);
    uint64_t* ws64 = (uint64_t*)ws;

    // ---------------- init ----------------
    if (tid < 24){
        const int uu = tid >> 2, gate = tid & 3;
        const int grow = gate*HDIM + g*UPW + uu;
        if (fp32in){
            lds_b[tid]      = ((const float*)bih0_)[grow] + ((const float*)bhh0_)[grow];
            lds_b[24 + tid] = ((const float*)bih1_)[grow] + ((const float*)bhh1_)[grow];
        } else {
            lds_b[tid]      = bf2f(((const uint16_t*)bih0_)[grow]) + bf2f(((const uint16_t*)bhh0_)[grow]);
            lds_b[24 + tid] = bf2f(((const uint16_t*)bih1_)[grow]) + bf2f(((const uint16_t*)bhh1_)[grow]);
        }
    }
    if (tid < 12){ lds_c[tid] = 0.f; lds_hout[tid] = 0.f; }

    // ---------------- persistent weight load (once) ----------------
    uint32_t w0[3][14];    // L0: 2 x-chunks (W_ih0) + 12 h-chunks (W_hh0), packed bf16
    uint32_t w1r[3][16];   // L1: chunks 8..11 (W_ih1) + 12..23 (W_hh1)

    if (fp32in){
        const float2* Wih0f = (const float2*)Wih0_;
        const float2* Whh0f = (const float2*)Whh0_;
        const float2* Wih1f = (const float2*)Wih1_;
        const float2* Whh1f = (const float2*)Whh1_;
        #pragma unroll
        for (int j = 0; j < 3; ++j){
            const int rr = w*3 + j;
            const int grow = (rr & 3)*HDIM + g*UPW + (rr >> 2);
            float2 t;
            t = Wih0f[grow*(DIN/2) + l];        w0[j][0] = packbf(t.x, t.y);
            t = Wih0f[grow*(DIN/2) + 64 + l];   w0[j][1] = packbf(t.x, t.y);
            #pragma unroll
            for (int c = 2; c < 14; ++c){
                t = Whh0f[grow*(HDIM/2) + (c-2)*64 + l]; w0[j][c] = packbf(t.x, t.y);
            }
            #pragma unroll
            for (int c = 0; c < 8; ++c){
                t = Wih1f[grow*(HDIM/2) + c*64 + l];
                lds_w[((w*3 + j)*8 + c)*64 + l] = packbf(t.x, t.y);
            }
            #pragma unroll
            for (int c = 8; c < 12; ++c){
                t = Wih1f[grow*(HDIM/2) + c*64 + l]; w1r[j][c-8] = packbf(t.x, t.y);
            }
            #pragma unroll
            for (int c = 12; c < 24; ++c){
                t = Whh1f[grow*(HDIM/2) + (c-12)*64 + l]; w1r[j][c-8] = packbf(t.x, t.y);
            }
        }
    } else {
        const uint32_t* Wih0p = (const uint32_t*)Wih0_;
        const uint32_t* Whh0p = (const uint32_t*)Whh0_;
        const uint32_t* Wih1p = (const uint32_t*)Wih1_;
        const uint32_t* Whh1p = (const uint32_t*)Whh1_;
        #pragma unroll
        for (int j = 0; j < 3; ++j){
            const int rr = w*3 + j;
            const int grow = (rr & 3)*HDIM + g*UPW + (rr >> 2);
            w0[j][0] = Wih0p[grow*(DIN/2) + l];
            w0[j][1] = Wih0p[grow*(DIN/2) + 64 + l];
            #pragma unroll
            for (int c = 2; c < 14; ++c)
                w0[j][c] = Whh0p[grow*(HDIM/2) + (c-2)*64 + l];
            #pragma unroll
            for (int c = 0; c < 8; ++c)
                lds_w[((w*3 + j)*8 + c)*64 + l] = Wih1p[grow*(HDIM/2) + c*64 + l];
            #pragma unroll
            for (int c = 8; c < 12; ++c)
                w1r[j][c-8] = Wih1p[grow*(HDIM/2) + c*64 + l];
            #pragma unroll
            for (int c = 12; c < 24; ++c)
                w1r[j][c-8] = Whh1p[grow*(HDIM/2) + (c-12)*64 + l];
        }
    }
    // lds_w consumed only after the first phase's __syncthreads.

    // ---------------- sequential phases ----------------
    // phase n computes layer0(t=n) [n<NSTEP] and layer1(t=n-1) [n>=1]
    for (int n = 0; n <= NSTEP; ++n){
        // x load issued first so it's in flight during the spin
        float xf[4];
        {
            const int nn = (n < NSTEP) ? n : 0;
            const int xbase = ((nn & 15)*64 + (nn >> 4) + 1) * XN;  // batch[b][ei]
            if (fp32in){
                const float2* bp = (const float2*)((const float*)batch_ + xbase);
                const float2 t0 = bp[l];        // elements 2l, 2l+1
                const float2 t1 = bp[64 + l];   // elements 128+2l, 128+2l+1
                xf[0] = t0.x; xf[1] = t0.y; xf[2] = t1.x; xf[3] = t1.y;
            } else {
                const uint32_t* bp = (const uint32_t*)batch_ + (xbase >> 1);
                const uint32_t t0 = bp[l], t1 = bp[64 + l];
                xf[0] = bflo(t0); xf[1] = bfhi(t0); xf[2] = bflo(t1); xf[3] = bfhi(t1);
            }
        }

        // spin on 3 tagged chunks per thread (fused barrier + h-load)
        uint64_t v0 = 0, v1 = 0, v2 = 0;
        {
            const uint64_t* h0c = ws64 + C_H0 + ((n+1) & 1)*768;  // h0(n-1)
            const uint64_t* h1c = ws64 + C_H1 + (n & 1)*768;      // h1(n-2)
            const uint64_t* a0 = h0c + tid;
            const uint64_t* a1 = (tid < 256) ? (h0c + 512 + tid) : (h1c + (tid - 256));
            const uint64_t* a2 = h1c + 256 + tid;
            const uint32_t want = (uint32_t)n;
            unsigned pend = 7u;
            while (pend){
                if (pend & 1u) v0 = __hip_atomic_load(a0, __ATOMIC_RELAXED, __HIP_MEMORY_SCOPE_AGENT);
                if (pend & 2u) v1 = __hip_atomic_load(a1, __ATOMIC_RELAXED, __HIP_MEMORY_SCOPE_AGENT);
                if (pend & 4u) v2 = __hip_atomic_load(a2, __ATOMIC_RELAXED, __HIP_MEMORY_SCOPE_AGENT);
                unsigned ok = 0;
                if ((uint32_t)(v0 >> 32) == want) ok |= 1u;
                if ((uint32_t)(v1 >> 32) == want) ok |= 2u;
                if ((uint32_t)(v2 >> 32) == want) ok |= 4u;
                pend &= ~ok;
                if (pend) __builtin_amdgcn_s_sleep(1);
            }
        }
        lds_h[tid]        = (uint32_t)v0;
        lds_h[tid + 512]  = (uint32_t)v1;
        lds_h[tid + 1024] = (uint32_t)v2;
        __syncthreads();

        // per-lane packed h fragments
        float h0f[24], h1f[24];
        #pragma unroll
        for (int k = 0; k < 12; ++k){
            const uint32_t p = lds_h[k*64 + l];
            h0f[2*k] = bflo(p); h0f[2*k+1] = bfhi(p);
        }
        #pragma unroll
        for (int k = 0; k < 12; ++k){
            const uint32_t p = lds_h[768 + k*64 + l];
            h1f[2*k] = bflo(p); h1f[2*k+1] = bfhi(p);
        }

        // dot products
        float acc0[3], acc1[3];
        #pragma unroll
        for (int j = 0; j < 3; ++j){
            float a = 0.f;
            a = fmaf(bflo(w0[j][0]), xf[0], a);
            a = fmaf(bfhi(w0[j][0]), xf[1], a);
            a = fmaf(bflo(w0[j][1]), xf[2], a);
            a = fmaf(bfhi(w0[j][1]), xf[3], a);
            #pragma unroll
            for (int c = 2; c < 14; ++c){
                a = fmaf(bflo(w0[j][c]), h0f[2*(c-2)],   a);
                a = fmaf(bfhi(w0[j][c]), h0f[2*(c-2)+1], a);
            }
            acc0[j] = a;
        }
        #pragma unroll
        for (int j = 0; j < 3; ++j){
            float a = 0.f;
            #pragma unroll
            for (int c = 0; c < 8; ++c){
                const uint32_t p = lds_w[((w*3 + j)*8 + c)*64 + l];
                a = fmaf(bflo(p), h0f[2*c],   a);
                a = fmaf(bfhi(p), h0f[2*c+1], a);
            }
            #pragma unroll
            for (int c = 8; c < 12; ++c){
                const uint32_t p = w1r[j][c-8];
                a = fmaf(bflo(p), h0f[2*c],   a);
                a = fmaf(bfhi(p), h0f[2*c+1], a);
            }
            #pragma unroll
            for (int c = 12; c < 24; ++c){
                const uint32_t p = w1r[j][c-8];
                a = fmaf(bflo(p), h1f[2*(c-12)],   a);
                a = fmaf(bfhi(p), h1f[2*(c-12)+1], a);
            }
            acc1[j] = a;
        }
        #pragma unroll
        for (int j = 0; j < 3; ++j){
            const float r0 = wave_sum(acc0[j]);
            const float r1 = wave_sum(acc1[j]);
            if (l == 0){
                lds_pre[w*3 + j]      = r0;
                lds_pre[24 + w*3 + j] = r1;
            }
        }
        __syncthreads();

        // cell update (wave 0 lanes 0..11) + packed publish via in-wave shfl
        if (w == 0){
            float hpub = 0.f;
            if (l < 12){
                const int layer = l / 6, uu = l % 6;
                const bool active = (layer == 0) ? (n < NSTEP) : (n >= 1);
                if (active){
                    const float* pre = &lds_pre[layer*24 + uu*4];
                    const float* bb  = &lds_b[layer*24 + uu*4];
                    const float gi = pre[0] + bb[0];
                    const float gf = pre[1] + bb[1];
                    const float gg = pre[2] + bb[2];
                    const float go = pre[3] + bb[3];
                    const float si = 1.f/(1.f + __expf(-gi));
                    const float sf = 1.f/(1.f + __expf(-gf));
                    const float so = 1.f/(1.f + __expf(-go));
                    const float cn = sf*lds_c[l] + si*tanh_fast(gg);
                    const float hn = so * tanh_fast(cn);
                    lds_c[l] = cn;
                    lds_hout[l] = hn;
                    hpub = hn;
                }
            }
            // all 64 lanes execute the shfl so source registers are valid
            const float lo = __shfl(hpub, (2*l) & 63, 64);
            const float hi = __shfl(hpub, (2*l + 1) & 63, 64);
            if (l < 6 && n < NSTEP){
                const uint64_t pk = ((uint64_t)(uint32_t)(n + 1) << 32)
                                  | (uint64_t)packbf(lo, hi);
                uint64_t* dst = (l < 3)
                    ? (ws64 + C_H0 + (n & 1)*768 + g*3 + l)
                    : (ws64 + C_H1 + ((n+1) & 1)*768 + g*3 + (l - 3));
                __hip_atomic_store(dst, pk, __ATOMIC_RELAXED, __HIP_MEMORY_SCOPE_AGENT);
            }
        }
        // no barrier: next phase's tag spin provides the sync
    }

    // ---------------- output: h[2][1536] ++ c[2][1536] ----------------
    if (tid < 12){
        const int layer = tid / 6, uu = tid % 6;
        const int oi = layer*HDIM + g*UPW + uu;
        if (fp32in){
            ((float*)out_)[oi]        = lds_hout[tid];
            ((float*)out_)[3072 + oi] = lds_c[tid];
        } else {
            ((uint16_t*)out_)[oi]        = f2bf(lds_hout[tid]);
            ((uint16_t*)out_)[3072 + oi] = f2bf(lds_c[tid]);
        }
    }
}

extern "C" void kernel_launch(void* const* d_in, const int* in_sizes, int n_in,
                              void* d_out, int out_size, void* d_ws, size_t ws_size,
                              hipStream_t stream)
{
    (void)in_sizes; (void)n_in; (void)out_size; (void)ws_size;
    const void* batch = d_in[0];
    const void* Wih0  = d_in[1];
    const void* Whh0  = d_in[2];
    const void* bih0  = d_in[3];
    const void* bhh0  = d_in[4];
    const void* Wih1  = d_in[5];
    const void* Whh1  = d_in[6];
    const void* bih1  = d_in[7];
    const void* bhh1  = d_in[8];
    void* out = d_out;
    uint32_t* ws = (uint32_t*)d_ws;

    hipLaunchKernelGGL(init_ws, dim3(3), dim3(256), 0, stream,
                       (const uint32_t*)Whh0, ws);

    void* args[] = { &batch, &Wih0, &Whh0, &bih0, &bhh0,
                     &Wih1, &Whh1, &bih1, &bhh1, &out, &ws };
    hipLaunchCooperativeKernel((const void*)lstm_seq_kernel,
                               dim3(NWG), dim3(TPB), args, 0, stream);
}

// Round 6
// 3643.570 us; speedup vs baseline: 8.1669x; 1.6758x over previous
//
#include <hip/hip_runtime.h>
#include <cstdint>

#define HDIM   1536
#define DIN    256
#define NSTEP  1008     // (T-1)*B = 63*16
#define NWG    256
#define TPB    512
#define UPW    6        // hidden units per WG per layer (256*6 = 1536)
#define XN     256      // x elements per step

// Exchange chunk: u64 = v0 | v1<<16 | v2<<32 | tag<<48  (3 bf16 h values + 16-bit tag)
// A "duplex" = 2 adjacent chunks = 6 values = one WG's per-layer output, 16B aligned.
// ws64 layout:
//   [0    .. 1023]  h0 chunks [2 parity][512]
//   [1024 .. 2047]  h1 chunks [2 parity][512]
// u32[4096] = dtype flag (1 = fp32 inputs, 0 = bf16 inputs)
// Producer phase p: h0(p) -> parity p&1, tag p+1 ; h1(p-1) -> parity (p+1)&1, tag p+1.
// Consumer phase n: wants tag n on h0 parity (n+1)&1 and h1 parity n&1.
#define C_H0      0
#define C_H1      1024
#define WS_FLAG_W 4096

typedef uint32_t u32x4 __attribute__((ext_vector_type(4)));

__device__ __forceinline__ float bflo(uint32_t p){ union{uint32_t u; float f;} v; v.u = p << 16; return v.f; }
__device__ __forceinline__ float bfhi(uint32_t p){ union{uint32_t u; float f;} v; v.u = p & 0xffff0000u; return v.f; }
__device__ __forceinline__ float bf2f(uint16_t b){ union{uint32_t u; float f;} v; v.u = ((uint32_t)b) << 16; return v.f; }
__device__ __forceinline__ uint16_t f2bf(float f){
    union{float f; uint32_t u;} v; v.f = f;
    uint32_t r = v.u + 0x7fffu + ((v.u >> 16) & 1u);   // RNE
    return (uint16_t)(r >> 16);
}
__device__ __forceinline__ uint32_t packbf(float lo, float hi){
    return (uint32_t)f2bf(lo) | ((uint32_t)f2bf(hi) << 16);
}
// inf-safe fast tanh: 1 - 2/(e^{2x}+1)
__device__ __forceinline__ float tanh_fast(float x){
    return 1.f - 2.f/(__expf(2.f*x) + 1.f);
}

// packed-bf16 2-way dot with fp32 accumulate
#if __has_builtin(__builtin_amdgcn_fdot2_f32_bf16)
typedef __bf16 bf16x2 __attribute__((ext_vector_type(2)));
__device__ __forceinline__ float dot2bf(uint32_t a, uint32_t b, float c){
    return __builtin_amdgcn_fdot2_f32_bf16(__builtin_bit_cast(bf16x2, a),
                                           __builtin_bit_cast(bf16x2, b), c, false);
}
#else
__device__ __forceinline__ float dot2bf(uint32_t a, uint32_t b, float c){
    c = fmaf(bflo(a), bflo(b), c);
    c = fmaf(bfhi(a), bfhi(b), c);
    return c;
}
#endif

// 16B system-coherent load (bypasses L1 + non-coherent XCD L2, reads LLC)
__device__ __forceinline__ u32x4 poll16(const uint64_t* p){
    u32x4 r;
    asm volatile("global_load_dwordx4 %0, %1, off sc0 sc1\n\t"
                 "s_waitcnt vmcnt(0)"
                 : "=v"(r) : "v"(p) : "memory");
    return r;
}

// sum across all 64 lanes, result in every lane
__device__ __forceinline__ float wave_sum(float x){
    #pragma unroll
    for (int o = 1; o < 64; o <<= 1) x += __shfl_xor(x, o, 64);
    return x;
}

// ---------------------------------------------------------------------------
// init kernel: seed boot chunks (zero h-state with boot tags) + dtype probe
// ---------------------------------------------------------------------------
__global__ void init_ws(const uint32_t* __restrict__ w, uint32_t* __restrict__ ws){
    uint64_t* ws64 = (uint64_t*)ws;
    const int i = blockIdx.x * blockDim.x + threadIdx.x;
    if (i < 512){
        ws64[C_H0 + 512 + i] = 0ull;                  // h0(-1): parity 1, tag 0, zeros
        ws64[C_H1 + i]       = 0ull;                  // h1(-2): parity 0, tag 0, zeros
        ws64[C_H1 + 512 + i] = ((uint64_t)1 << 48);   // h1(-1): parity 1, tag 1, zeros
    }
    if (blockIdx.x == 0 && threadIdx.x < 64){
        const int t = threadIdx.x;
        int cnt = 0;
        #pragma unroll
        for (int j = 0; j < 4; ++j){
            const uint32_t v = w[t*4 + j];
            const uint32_t e = (v >> 7) & 0xFFu;
            if (e == 0u || (e >= 0x70u && e <= 0x7Cu)) cnt++;
        }
        #pragma unroll
        for (int o = 1; o < 64; o <<= 1) cnt += __shfl_xor(cnt, o, 64);
        if (t == 0)
            ws[WS_FLAG_W] = (cnt < 128) ? 1u : 0u;   // sparse in-window => fp32
    }
}

__global__ __launch_bounds__(TPB, 2)
void lstm_seq_kernel(const void* __restrict__ batch_,
                     const void* __restrict__ Wih0_,
                     const void* __restrict__ Whh0_,
                     const void* __restrict__ bih0_,
                     const void* __restrict__ bhh0_,
                     const void* __restrict__ Wih1_,
                     const void* __restrict__ Whh1_,
                     const void* __restrict__ bih1_,
                     const void* __restrict__ bhh1_,
                     void* __restrict__ out_,
                     uint32_t* __restrict__ ws)
{
    __shared__ uint32_t lds_w[8*3*8*64];   // L1 rows, h0-chunks 0..7 (packed bf16)
    __shared__ uint32_t lds_h[1536];       // packed h pairs: [0..767]=h0, [768..1535]=h1
    __shared__ float    lds_pre[48];       // 24 L0 + 24 L1 pre-activations
    __shared__ float    lds_b[48];         // fused biases
    __shared__ float    lds_c[12];         // c-state
    __shared__ float    lds_hout[12];      // h-state (fp32)

    const int g   = blockIdx.x;
    const int tid = threadIdx.x;
    const int w   = tid >> 6;
    const int l   = tid & 63;

    const uint32_t fp32in = __hip_atomic_load(&ws[WS_FLAG_W],
                             __ATOMIC_RELAXED, __HIP_MEMORY_SCOPE_AGENT);
    uint64_t* ws64 = (uint64_t*)ws;

    // ---------------- init ----------------
    if (tid < 24){
        const int uu = tid >> 2, gate = tid & 3;
        const int grow = gate*HDIM + g*UPW + uu;
        if (fp32in){
            lds_b[tid]      = ((const float*)bih0_)[grow] + ((const float*)bhh0_)[grow];
            lds_b[24 + tid] = ((const float*)bih1_)[grow] + ((const float*)bhh1_)[grow];
        } else {
            lds_b[tid]      = bf2f(((const uint16_t*)bih0_)[grow]) + bf2f(((const uint16_t*)bhh0_)[grow]);
            lds_b[24 + tid] = bf2f(((const uint16_t*)bih1_)[grow]) + bf2f(((const uint16_t*)bhh1_)[grow]);
        }
    }
    if (tid < 12){ lds_c[tid] = 0.f; lds_hout[tid] = 0.f; }

    // ---------------- persistent weight load (once) ----------------
    uint32_t w0[3][14];    // L0: 2 x-chunks (W_ih0) + 12 h-chunks (W_hh0), packed bf16
    uint32_t w1r[3][16];   // L1: chunks 8..11 (W_ih1) + 12..23 (W_hh1)

    if (fp32in){
        const float2* Wih0f = (const float2*)Wih0_;
        const float2* Whh0f = (const float2*)Whh0_;
        const float2* Wih1f = (const float2*)Wih1_;
        const float2* Whh1f = (const float2*)Whh1_;
        #pragma unroll
        for (int j = 0; j < 3; ++j){
            const int rr = w*3 + j;
            const int grow = (rr & 3)*HDIM + g*UPW + (rr >> 2);
            float2 t;
            t = Wih0f[grow*(DIN/2) + l];        w0[j][0] = packbf(t.x, t.y);
            t = Wih0f[grow*(DIN/2) + 64 + l];   w0[j][1] = packbf(t.x, t.y);
            #pragma unroll
            for (int c = 2; c < 14; ++c){
                t = Whh0f[grow*(HDIM/2) + (c-2)*64 + l]; w0[j][c] = packbf(t.x, t.y);
            }
            #pragma unroll
            for (int c = 0; c < 8; ++c){
                t = Wih1f[grow*(HDIM/2) + c*64 + l];
                lds_w[((w*3 + j)*8 + c)*64 + l] = packbf(t.x, t.y);
            }
            #pragma unroll
            for (int c = 8; c < 12; ++c){
                t = Wih1f[grow*(HDIM/2) + c*64 + l]; w1r[j][c-8] = packbf(t.x, t.y);
            }
            #pragma unroll
            for (int c = 12; c < 24; ++c){
                t = Whh1f[grow*(HDIM/2) + (c-12)*64 + l]; w1r[j][c-8] = packbf(t.x, t.y);
            }
        }
    } else {
        const uint32_t* Wih0p = (const uint32_t*)Wih0_;
        const uint32_t* Whh0p = (const uint32_t*)Whh0_;
        const uint32_t* Wih1p = (const uint32_t*)Wih1_;
        const uint32_t* Whh1p = (const uint32_t*)Whh1_;
        #pragma unroll
        for (int j = 0; j < 3; ++j){
            const int rr = w*3 + j;
            const int grow = (rr & 3)*HDIM + g*UPW + (rr >> 2);
            w0[j][0] = Wih0p[grow*(DIN/2) + l];
            w0[j][1] = Wih0p[grow*(DIN/2) + 64 + l];
            #pragma unroll
            for (int c = 2; c < 14; ++c)
                w0[j][c] = Whh0p[grow*(HDIM/2) + (c-2)*64 + l];
            #pragma unroll
            for (int c = 0; c < 8; ++c)
                lds_w[((w*3 + j)*8 + c)*64 + l] = Wih1p[grow*(HDIM/2) + c*64 + l];
            #pragma unroll
            for (int c = 8; c < 12; ++c)
                w1r[j][c-8] = Wih1p[grow*(HDIM/2) + c*64 + l];
            #pragma unroll
            for (int c = 12; c < 24; ++c)
                w1r[j][c-8] = Whh1p[grow*(HDIM/2) + (c-12)*64 + l];
        }
    }
    // lds_w consumed only after the first phase's __syncthreads.

    // poll address components (constant across phases except parity)
    const int players = tid >> 8;          // 0 = h0, 1 = h1
    const int pidx    = tid & 255;         // duplex index (producer WG id)

    // ---------------- sequential phases ----------------
    // phase n computes layer0(t=n) [n<NSTEP] and layer1(t=n-1) [n>=1]
    for (int n = 0; n <= NSTEP; ++n){
        // x load issued first so it's in flight during the spin
        uint32_t xp0, xp1;
        {
            const int nn = (n < NSTEP) ? n : 0;
            const int xbase = ((nn & 15)*64 + (nn >> 4) + 1) * XN;  // batch[b][ei]
            if (fp32in){
                const float2* bp = (const float2*)((const float*)batch_ + xbase);
                const float2 t0 = bp[l];
                const float2 t1 = bp[64 + l];
                xp0 = packbf(t0.x, t0.y); xp1 = packbf(t1.x, t1.y);
            } else {
                const uint32_t* bp = (const uint32_t*)batch_ + (xbase >> 1);
                xp0 = bp[l]; xp1 = bp[64 + l];
            }
        }

        // one 16B poll per thread: a duplex = 2 self-tagged chunks = 6 h values
        u32x4 r;
        {
            const uint64_t* ap = ws64
                + (players ? (C_H1 + (n & 1)*512) : (C_H0 + ((n+1) & 1)*512))
                + 2*pidx;
            const uint32_t want = (uint32_t)n & 0xFFFFu;
            r = poll16(ap);
            while ((r.y >> 16) != want || (r.w >> 16) != want){
                __builtin_amdgcn_s_sleep(2);
                r = poll16(ap);
            }
        }
        {
            const int base = players*768 + 3*pidx;
            lds_h[base]     = r.x;                                   // v0|v1
            lds_h[base + 1] = (r.y & 0xFFFFu) | (r.z << 16);         // v2|v3
            lds_h[base + 2] = (r.z >> 16)     | (r.w << 16);         // v4|v5
        }
        __syncthreads();

        // per-lane packed h pairs
        uint32_t h0p[12], h1p[12];
        #pragma unroll
        for (int k = 0; k < 12; ++k) h0p[k] = lds_h[k*64 + l];
        #pragma unroll
        for (int k = 0; k < 12; ++k) h1p[k] = lds_h[768 + k*64 + l];

        // dot products (packed bf16 dot2, fp32 accumulate)
        float acc0[3], acc1[3];
        #pragma unroll
        for (int j = 0; j < 3; ++j){
            float a = dot2bf(w0[j][0], xp0, 0.f);
            a = dot2bf(w0[j][1], xp1, a);
            #pragma unroll
            for (int k = 0; k < 12; ++k)
                a = dot2bf(w0[j][k+2], h0p[k], a);
            acc0[j] = a;
        }
        #pragma unroll
        for (int j = 0; j < 3; ++j){
            float a = 0.f;
            #pragma unroll
            for (int k = 0; k < 8; ++k)
                a = dot2bf(lds_w[((w*3 + j)*8 + k)*64 + l], h0p[k], a);
            #pragma unroll
            for (int k = 8; k < 12; ++k)
                a = dot2bf(w1r[j][k-8], h0p[k], a);
            #pragma unroll
            for (int k = 0; k < 12; ++k)
                a = dot2bf(w1r[j][k+4], h1p[k], a);
            acc1[j] = a;
        }
        #pragma unroll
        for (int j = 0; j < 3; ++j){
            const float r0 = wave_sum(acc0[j]);
            const float r1 = wave_sum(acc1[j]);
            if (l == 0){
                lds_pre[w*3 + j]      = r0;
                lds_pre[24 + w*3 + j] = r1;
            }
        }
        __syncthreads();

        // cell update (wave 0 lanes 0..11) + duplex publish via in-wave shfl
        if (w == 0){
            float hpub = 0.f;
            if (l < 12){
                const int layer = l / 6, uu = l % 6;
                const bool active = (layer == 0) ? (n < NSTEP) : (n >= 1);
                if (active){
                    const float* pre = &lds_pre[layer*24 + uu*4];
                    const float* bb  = &lds_b[layer*24 + uu*4];
                    const float gi = pre[0] + bb[0];
                    const float gf = pre[1] + bb[1];
                    const float gg = pre[2] + bb[2];
                    const float go = pre[3] + bb[3];
                    const float si = 1.f/(1.f + __expf(-gi));
                    const float sf = 1.f/(1.f + __expf(-gf));
                    const float so = 1.f/(1.f + __expf(-go));
                    const float cn = sf*lds_c[l] + si*tanh_fast(gg);
                    const float hn = so * tanh_fast(cn);
                    lds_c[l] = cn;
                    lds_hout[l] = hn;
                    hpub = hn;
                }
            }
            // builder lanes 0..3 gather 3 values each (all lanes execute shfl)
            const float s0 = __shfl(hpub, (3*l)     & 63, 64);
            const float s1 = __shfl(hpub, (3*l + 1) & 63, 64);
            const float s2 = __shfl(hpub, (3*l + 2) & 63, 64);
            if (l < 4 && n < NSTEP){
                const bool isL1 = (l >= 2);
                if (!isL1 || n >= 1){
                    const uint64_t tag = (uint64_t)((uint32_t)(n + 1) & 0xFFFFu);
                    const uint64_t pk = (uint64_t)f2bf(s0)
                                      | ((uint64_t)f2bf(s1) << 16)
                                      | ((uint64_t)f2bf(s2) << 32)
                                      | (tag << 48);
                    uint64_t* dst = isL1
                        ? (ws64 + C_H1 + ((n+1) & 1)*512 + 2*g + (l - 2))
                        : (ws64 + C_H0 + (n & 1)*512 + 2*g + l);
                    __hip_atomic_store(dst, pk, __ATOMIC_RELAXED, __HIP_MEMORY_SCOPE_AGENT);
                }
            }
        }
        // no barrier: next phase's tag spin provides the sync
    }

    // ---------------- output: h[2][1536] ++ c[2][1536] ----------------
    if (tid < 12){
        const int layer = tid / 6, uu = tid % 6;
        const int oi = layer*HDIM + g*UPW + uu;
        if (fp32in){
            ((float*)out_)[oi]        = lds_hout[tid];
            ((float*)out_)[3072 + oi] = lds_c[tid];
        } else {
            ((uint16_t*)out_)[oi]        = f2bf(lds_hout[tid]);
            ((uint16_t*)out_)[3072 + oi] = f2bf(lds_c[tid]);
        }
    }
}

extern "C" void kernel_launch(void* const* d_in, const int* in_sizes, int n_in,
                              void* d_out, int out_size, void* d_ws, size_t ws_size,
                              hipStream_t stream)
{
    (void)in_sizes; (void)n_in; (void)out_size; (void)ws_size;
    const void* batch = d_in[0];
    const void* Wih0  = d_in[1];
    const void* Whh0  = d_in[2];
    const void* bih0  = d_in[3];
    const void* bhh0  = d_in[4];
    const void* Wih1  = d_in[5];
    const void* Whh1  = d_in[6];
    const void* bih1  = d_in[7];
    const void* bhh1  = d_in[8];
    void* out = d_out;
    uint32_t* ws = (uint32_t*)d_ws;

    hipLaunchKernelGGL(init_ws, dim3(2), dim3(256), 0, stream,
                       (const uint32_t*)Whh0, ws);

    void* args[] = { &batch, &Wih0, &Whh0, &bih0, &bhh0,
                     &Wih1, &Whh1, &bih1, &bhh1, &out, &ws };
    hipLaunchCooperativeKernel((const void*)lstm_seq_kernel,
                               dim3(NWG), dim3(TPB), args, 0, stream);
}

// Round 7
// 3505.922 us; speedup vs baseline: 8.4875x; 1.0393x over previous
//
#include <hip/hip_runtime.h>
#include <cstdint>

#define HDIM   1536
#define DIN    256
#define NSTEP  1008     // (T-1)*B = 63*16
#define NWG    256
#define TPB    512
#define UPW    6        // hidden units per WG per layer (256*6 = 1536)
#define XN     256      // x elements per step
#define NREP   8        // exchange replicas (spread LLC line contention)

// Exchange chunk: u64 = v0 | v1<<16 | v2<<32 | tag<<48  (3 bf16 h values + 16-bit tag)
// A "duplex" = 2 adjacent chunks = 6 values = one WG's per-layer output, 16B aligned.
// Replica r occupies ws64[r*2048 .. r*2048+2047], layout within a replica:
//   [0    .. 1023]  h0 chunks [2 parity][512]
//   [1024 .. 2047]  h1 chunks [2 parity][512]
// u32[32768] = dtype flag (1 = fp32 inputs, 0 = bf16 inputs)
// Producer phase p: h0(p) -> parity p&1, tag p+1 ; h1(p-1) -> parity (p+1)&1, tag p+1.
// Consumer phase n: wants tag n on h0 parity (n+1)&1 and h1 parity n&1.
#define C_H0      0
#define C_H1      1024
#define REP_STRIDE 2048
#define WS_FLAG_W 32768

typedef uint32_t u32x4 __attribute__((ext_vector_type(4)));

__device__ __forceinline__ float bflo(uint32_t p){ union{uint32_t u; float f;} v; v.u = p << 16; return v.f; }
__device__ __forceinline__ float bfhi(uint32_t p){ union{uint32_t u; float f;} v; v.u = p & 0xffff0000u; return v.f; }
__device__ __forceinline__ float bf2f(uint16_t b){ union{uint32_t u; float f;} v; v.u = ((uint32_t)b) << 16; return v.f; }
__device__ __forceinline__ uint16_t f2bf(float f){
    union{float f; uint32_t u;} v; v.f = f;
    uint32_t r = v.u + 0x7fffu + ((v.u >> 16) & 1u);   // RNE
    return (uint16_t)(r >> 16);
}
__device__ __forceinline__ uint32_t packbf(float lo, float hi){
    return (uint32_t)f2bf(lo) | ((uint32_t)f2bf(hi) << 16);
}
// inf-safe fast tanh: 1 - 2/(e^{2x}+1)
__device__ __forceinline__ float tanh_fast(float x){
    return 1.f - 2.f/(__expf(2.f*x) + 1.f);
}

// packed-bf16 2-way dot with fp32 accumulate
#if __has_builtin(__builtin_amdgcn_fdot2_f32_bf16)
typedef __bf16 bf16x2 __attribute__((ext_vector_type(2)));
__device__ __forceinline__ float dot2bf(uint32_t a, uint32_t b, float c){
    return __builtin_amdgcn_fdot2_f32_bf16(__builtin_bit_cast(bf16x2, a),
                                           __builtin_bit_cast(bf16x2, b), c, false);
}
#else
__device__ __forceinline__ float dot2bf(uint32_t a, uint32_t b, float c){
    c = fmaf(bflo(a), bflo(b), c);
    c = fmaf(bfhi(a), bfhi(b), c);
    return c;
}
#endif

// 16B system-coherent load (bypasses L1 + non-coherent XCD L2, reads LLC)
__device__ __forceinline__ u32x4 poll16(const uint64_t* p){
    u32x4 r;
    asm volatile("global_load_dwordx4 %0, %1, off sc0 sc1\n\t"
                 "s_waitcnt vmcnt(0)"
                 : "=v"(r) : "v"(p) : "memory");
    return r;
}

// sum across all 64 lanes, result in every lane
__device__ __forceinline__ float wave_sum(float x){
    #pragma unroll
    for (int o = 1; o < 64; o <<= 1) x += __shfl_xor(x, o, 64);
    return x;
}

// ---------------------------------------------------------------------------
// init kernel: seed boot chunks in all replicas + dtype probe
// ---------------------------------------------------------------------------
__global__ void init_ws(const uint32_t* __restrict__ w, uint32_t* __restrict__ ws){
    uint64_t* ws64 = (uint64_t*)ws;
    const int i = blockIdx.x * blockDim.x + threadIdx.x;   // 0 .. NREP*512-1
    if (i < NREP*512){
        const int rep = i >> 9, j = i & 511;
        uint64_t* base = ws64 + rep*REP_STRIDE;
        base[C_H0 + 512 + j] = 0ull;                  // h0(-1): parity 1, tag 0, zeros
        base[C_H1 + j]       = 0ull;                  // h1(-2): parity 0, tag 0, zeros
        base[C_H1 + 512 + j] = ((uint64_t)1 << 48);   // h1(-1): parity 1, tag 1, zeros
    }
    if (blockIdx.x == 0 && threadIdx.x < 64){
        const int t = threadIdx.x;
        int cnt = 0;
        #pragma unroll
        for (int j = 0; j < 4; ++j){
            const uint32_t v = w[t*4 + j];
            const uint32_t e = (v >> 7) & 0xFFu;
            if (e == 0u || (e >= 0x70u && e <= 0x7Cu)) cnt++;
        }
        #pragma unroll
        for (int o = 1; o < 64; o <<= 1) cnt += __shfl_xor(cnt, o, 64);
        if (t == 0)
            ws[WS_FLAG_W] = (cnt < 128) ? 1u : 0u;   // sparse in-window => fp32
    }
}

__global__ __launch_bounds__(TPB, 2)
void lstm_seq_kernel(const void* __restrict__ batch_,
                     const void* __restrict__ Wih0_,
                     const void* __restrict__ Whh0_,
                     const void* __restrict__ bih0_,
                     const void* __restrict__ bhh0_,
                     const void* __restrict__ Wih1_,
                     const void* __restrict__ Whh1_,
                     const void* __restrict__ bih1_,
                     const void* __restrict__ bhh1_,
                     void* __restrict__ out_,
                     uint32_t* __restrict__ ws)
{
    __shared__ uint32_t lds_w[8*3*8*64];   // L1 rows, h0-chunks 0..7 (packed bf16)
    __shared__ uint32_t lds_h[1536];       // packed h pairs: [0..767]=h0, [768..1535]=h1
    __shared__ float    lds_pre[48];       // 24 L0 + 24 L1 pre-activations
    __shared__ float    lds_b[48];         // fused biases
    __shared__ float    lds_c[12];         // c-state
    __shared__ float    lds_hout[12];      // h-state (fp32)

    const int g   = blockIdx.x;
    const int tid = threadIdx.x;
    const int w   = tid >> 6;
    const int l   = tid & 63;

    const uint32_t fp32in = __hip_atomic_load(&ws[WS_FLAG_W],
                             __ATOMIC_RELAXED, __HIP_MEMORY_SCOPE_AGENT);
    uint64_t* ws64 = (uint64_t*)ws;

    // ---------------- init ----------------
    if (tid < 24){
        const int uu = tid >> 2, gate = tid & 3;
        const int grow = gate*HDIM + g*UPW + uu;
        if (fp32in){
            lds_b[tid]      = ((const float*)bih0_)[grow] + ((const float*)bhh0_)[grow];
            lds_b[24 + tid] = ((const float*)bih1_)[grow] + ((const float*)bhh1_)[grow];
        } else {
            lds_b[tid]      = bf2f(((const uint16_t*)bih0_)[grow]) + bf2f(((const uint16_t*)bhh0_)[grow]);
            lds_b[24 + tid] = bf2f(((const uint16_t*)bih1_)[grow]) + bf2f(((const uint16_t*)bhh1_)[grow]);
        }
    }
    if (tid < 12){ lds_c[tid] = 0.f; lds_hout[tid] = 0.f; }

    // ---------------- persistent weight load (once) ----------------
    uint32_t w0[3][14];    // L0: 2 x-chunks (W_ih0) + 12 h-chunks (W_hh0), packed bf16
    uint32_t w1r[3][16];   // L1: chunks 8..11 (W_ih1) + 12..23 (W_hh1)

    if (fp32in){
        const float2* Wih0f = (const float2*)Wih0_;
        const float2* Whh0f = (const float2*)Whh0_;
        const float2* Wih1f = (const float2*)Wih1_;
        const float2* Whh1f = (const float2*)Whh1_;
        #pragma unroll
        for (int j = 0; j < 3; ++j){
            const int rr = w*3 + j;
            const int grow = (rr & 3)*HDIM + g*UPW + (rr >> 2);
            float2 t;
            t = Wih0f[grow*(DIN/2) + l];        w0[j][0] = packbf(t.x, t.y);
            t = Wih0f[grow*(DIN/2) + 64 + l];   w0[j][1] = packbf(t.x, t.y);
            #pragma unroll
            for (int c = 2; c < 14; ++c){
                t = Whh0f[grow*(HDIM/2) + (c-2)*64 + l]; w0[j][c] = packbf(t.x, t.y);
            }
            #pragma unroll
            for (int c = 0; c < 8; ++c){
                t = Wih1f[grow*(HDIM/2) + c*64 + l];
                lds_w[((w*3 + j)*8 + c)*64 + l] = packbf(t.x, t.y);
            }
            #pragma unroll
            for (int c = 8; c < 12; ++c){
                t = Wih1f[grow*(HDIM/2) + c*64 + l]; w1r[j][c-8] = packbf(t.x, t.y);
            }
            #pragma unroll
            for (int c = 12; c < 24; ++c){
                t = Whh1f[grow*(HDIM/2) + (c-12)*64 + l]; w1r[j][c-8] = packbf(t.x, t.y);
            }
        }
    } else {
        const uint32_t* Wih0p = (const uint32_t*)Wih0_;
        const uint32_t* Whh0p = (const uint32_t*)Whh0_;
        const uint32_t* Wih1p = (const uint32_t*)Wih1_;
        const uint32_t* Whh1p = (const uint32_t*)Whh1_;
        #pragma unroll
        for (int j = 0; j < 3; ++j){
            const int rr = w*3 + j;
            const int grow = (rr & 3)*HDIM + g*UPW + (rr >> 2);
            w0[j][0] = Wih0p[grow*(DIN/2) + l];
            w0[j][1] = Wih0p[grow*(DIN/2) + 64 + l];
            #pragma unroll
            for (int c = 2; c < 14; ++c)
                w0[j][c] = Whh0p[grow*(HDIM/2) + (c-2)*64 + l];
            #pragma unroll
            for (int c = 0; c < 8; ++c)
                lds_w[((w*3 + j)*8 + c)*64 + l] = Wih1p[grow*(HDIM/2) + c*64 + l];
            #pragma unroll
            for (int c = 8; c < 12; ++c)
                w1r[j][c-8] = Wih1p[grow*(HDIM/2) + c*64 + l];
            #pragma unroll
            for (int c = 12; c < 24; ++c)
                w1r[j][c-8] = Whh1p[grow*(HDIM/2) + (c-12)*64 + l];
        }
    }
    // lds_w consumed only after the first phase's __syncthreads.

    // poll address components (constant across phases except parity)
    const int players = tid >> 8;          // 0 = h0, 1 = h1
    const int pidx    = tid & 255;         // duplex index (producer WG id)
    uint64_t* myrep   = ws64 + (g & (NREP-1))*REP_STRIDE;   // this WG's poll replica

    // ---------------- sequential phases ----------------
    // phase n computes layer0(t=n) [n<NSTEP] and layer1(t=n-1) [n>=1]
    for (int n = 0; n <= NSTEP; ++n){
        // x load issued first so it's in flight during the spin
        uint32_t xp0, xp1;
        {
            const int nn = (n < NSTEP) ? n : 0;
            const int xbase = ((nn & 15)*64 + (nn >> 4) + 1) * XN;  // batch[b][ei]
            if (fp32in){
                const float2* bp = (const float2*)((const float*)batch_ + xbase);
                const float2 t0 = bp[l];
                const float2 t1 = bp[64 + l];
                xp0 = packbf(t0.x, t0.y); xp1 = packbf(t1.x, t1.y);
            } else {
                const uint32_t* bp = (const uint32_t*)batch_ + (xbase >> 1);
                xp0 = bp[l]; xp1 = bp[64 + l];
            }
        }

        // one 16B poll per thread: a duplex = 2 self-tagged chunks = 6 h values
        u32x4 r;
        {
            const uint64_t* ap = myrep
                + (players ? (C_H1 + (n & 1)*512) : (C_H0 + ((n+1) & 1)*512))
                + 2*pidx;
            const uint32_t want = (uint32_t)n & 0xFFFFu;
            r = poll16(ap);
            while ((r.y >> 16) != want || (r.w >> 16) != want){
                __builtin_amdgcn_s_sleep(1);
                r = poll16(ap);
            }
        }
        {
            const int base = players*768 + 3*pidx;
            lds_h[base]     = r.x;                                   // v0|v1
            lds_h[base + 1] = (r.y & 0xFFFFu) | (r.z << 16);         // v2|v3
            lds_h[base + 2] = (r.z >> 16)     | (r.w << 16);         // v4|v5
        }
        __syncthreads();

        // per-lane packed h pairs
        uint32_t h0p[12], h1p[12];
        #pragma unroll
        for (int k = 0; k < 12; ++k) h0p[k] = lds_h[k*64 + l];
        #pragma unroll
        for (int k = 0; k < 12; ++k) h1p[k] = lds_h[768 + k*64 + l];

        // dot products (packed bf16 dot2, fp32 accumulate)
        float acc0[3], acc1[3];
        #pragma unroll
        for (int j = 0; j < 3; ++j){
            float a = dot2bf(w0[j][0], xp0, 0.f);
            a = dot2bf(w0[j][1], xp1, a);
            #pragma unroll
            for (int k = 0; k < 12; ++k)
                a = dot2bf(w0[j][k+2], h0p[k], a);
            acc0[j] = a;
        }
        #pragma unroll
        for (int j = 0; j < 3; ++j){
            float a = 0.f;
            #pragma unroll
            for (int k = 0; k < 8; ++k)
                a = dot2bf(lds_w[((w*3 + j)*8 + k)*64 + l], h0p[k], a);
            #pragma unroll
            for (int k = 8; k < 12; ++k)
                a = dot2bf(w1r[j][k-8], h0p[k], a);
            #pragma unroll
            for (int k = 0; k < 12; ++k)
                a = dot2bf(w1r[j][k+4], h1p[k], a);
            acc1[j] = a;
        }
        #pragma unroll
        for (int j = 0; j < 3; ++j){
            const float r0 = wave_sum(acc0[j]);
            const float r1 = wave_sum(acc1[j]);
            if (l == 0){
                lds_pre[w*3 + j]      = r0;
                lds_pre[24 + w*3 + j] = r1;
            }
        }
        __syncthreads();

        // cell update (wave 0 lanes 0..11) + replicated duplex publish
        if (w == 0){
            float hpub = 0.f;
            if (l < 12){
                const int layer = l / 6, uu = l % 6;
                const bool active = (layer == 0) ? (n < NSTEP) : (n >= 1);
                if (active){
                    const float* pre = &lds_pre[layer*24 + uu*4];
                    const float* bb  = &lds_b[layer*24 + uu*4];
                    const float gi = pre[0] + bb[0];
                    const float gf = pre[1] + bb[1];
                    const float gg = pre[2] + bb[2];
                    const float go = pre[3] + bb[3];
                    const float si = 1.f/(1.f + __expf(-gi));
                    const float sf = 1.f/(1.f + __expf(-gf));
                    const float so = 1.f/(1.f + __expf(-go));
                    const float cn = sf*lds_c[l] + si*tanh_fast(gg);
                    const float hn = so * tanh_fast(cn);
                    lds_c[l] = cn;
                    lds_hout[l] = hn;
                    hpub = hn;
                }
            }
            // lanes 0..31: replica = l>>2, chunk slot = l&3 (all lanes run shfl)
            const int slot = l & 3;
            const int b3 = 3*slot;
            const float s0 = __shfl(hpub, b3,     64);
            const float s1 = __shfl(hpub, b3 + 1, 64);
            const float s2 = __shfl(hpub, b3 + 2, 64);
            if (l < 4*NREP && n < NSTEP){
                const bool isL1 = (slot >= 2);
                if (!isL1 || n >= 1){
                    const uint64_t tag = (uint64_t)((uint32_t)(n + 1) & 0xFFFFu);
                    const uint64_t pk = (uint64_t)f2bf(s0)
                                      | ((uint64_t)f2bf(s1) << 16)
                                      | ((uint64_t)f2bf(s2) << 32)
                                      | (tag << 48);
                    uint64_t* dst = ws64 + (l >> 2)*REP_STRIDE
                        + (isL1 ? (C_H1 + ((n+1) & 1)*512 + 2*g + (slot - 2))
                                : (C_H0 + (n & 1)*512 + 2*g + slot));
                    __hip_atomic_store(dst, pk, __ATOMIC_RELAXED, __HIP_MEMORY_SCOPE_AGENT);
                }
            }
        }
        // no barrier: next phase's tag spin provides the sync
    }

    // ---------------- output: h[2][1536] ++ c[2][1536] ----------------
    if (tid < 12){
        const int layer = tid / 6, uu = tid % 6;
        const int oi = layer*HDIM + g*UPW + uu;
        if (fp32in){
            ((float*)out_)[oi]        = lds_hout[tid];
            ((float*)out_)[3072 + oi] = lds_c[tid];
        } else {
            ((uint16_t*)out_)[oi]        = f2bf(lds_hout[tid]);
            ((uint16_t*)out_)[3072 + oi] = f2bf(lds_c[tid]);
        }
    }
}

extern "C" void kernel_launch(void* const* d_in, const int* in_sizes, int n_in,
                              void* d_out, int out_size, void* d_ws, size_t ws_size,
                              hipStream_t stream)
{
    (void)in_sizes; (void)n_in; (void)out_size; (void)ws_size;
    const void* batch = d_in[0];
    const void* Wih0  = d_in[1];
    const void* Whh0  = d_in[2];
    const void* bih0  = d_in[3];
    const void* bhh0  = d_in[4];
    const void* Wih1  = d_in[5];
    const void* Whh1  = d_in[6];
    const void* bih1  = d_in[7];
    const void* bhh1  = d_in[8];
    void* out = d_out;
    uint32_t* ws = (uint32_t*)d_ws;

    hipLaunchKernelGGL(init_ws, dim3((NREP*512 + 255)/256), dim3(256), 0, stream,
                       (const uint32_t*)Whh0, ws);

    void* args[] = { &batch, &Wih0, &Whh0, &bih0, &bhh0,
                     &Wih1, &Whh1, &bih1, &bhh1, &out, &ws };
    hipLaunchCooperativeKernel((const void*)lstm_seq_kernel,
                               dim3(NWG), dim3(TPB), args, 0, stream);
}